// Round 4
// baseline (695.785 us; speedup 1.0000x reference)
//
#include <hip/hip_runtime.h>
#include <math.h>

// ---------------------------------------------------------------------------
// SymmetricalResidualGAT: EdgeConv(max) + GAT x4 (H=2, C=128) + linears.
// N=20000, E=320000. Round 4: zero-LDS barrier-free MFMA GEMM with
// producer-side bf16 hi/lo splitting of activations.
// ---------------------------------------------------------------------------

#define NEG_SLOPE 0.2f

typedef short short8 __attribute__((ext_vector_type(8)));
typedef float float4v __attribute__((ext_vector_type(4)));
typedef unsigned short ushort4v __attribute__((ext_vector_type(4)));

__device__ __forceinline__ float leaky(float x) { return x > 0.f ? x : NEG_SLOPE * x; }

__device__ __forceinline__ void atomicMaxF(float* addr, float v) {
  if (v >= 0.f) atomicMax((int*)addr, __float_as_int(v));
  else          atomicMin((unsigned int*)addr, __float_as_uint(v));
}

__device__ __forceinline__ unsigned short bf16_rn(float f) {
  unsigned u = __float_as_uint(f);
  unsigned r = (u + 0x7FFFu + ((u >> 16) & 1u)) >> 16;
  return (unsigned short)r;
}
__device__ __forceinline__ float bf16_to_f(unsigned short h) {
  return __uint_as_float(((unsigned)h) << 16);
}

// ---------------- small kernels ----------------
__global__ __launch_bounds__(256) void k_fill_f32(float* p, float v, int n) {
  int i = blockIdx.x * 256 + threadIdx.x;
  if (i < n) p[i] = v;
}

// split fp32 activations -> bf16 hi/lo; optionally map -inf -> 0 (edgeconv max)
__global__ __launch_bounds__(256) void k_split_act(const float* __restrict__ src,
                                                   unsigned short* __restrict__ h,
                                                   unsigned short* __restrict__ l,
                                                   int n, int fixinf) {
  int i4 = (blockIdx.x * 256 + threadIdx.x) * 4;
  if (i4 >= n) return;
  float4 v = *(const float4*)&src[i4];
  if (fixinf) {
    if (v.x == -INFINITY) v.x = 0.f;
    if (v.y == -INFINITY) v.y = 0.f;
    if (v.z == -INFINITY) v.z = 0.f;
    if (v.w == -INFINITY) v.w = 0.f;
  }
  unsigned short hx = bf16_rn(v.x), hy = bf16_rn(v.y), hz = bf16_rn(v.z), hw = bf16_rn(v.w);
  ushort4v h4 = {hx, hy, hz, hw};
  ushort4v l4 = {bf16_rn(v.x - bf16_to_f(hx)), bf16_rn(v.y - bf16_to_f(hy)),
                 bf16_rn(v.z - bf16_to_f(hz)), bf16_rn(v.w - bf16_to_f(hw))};
  *(ushort4v*)&h[i4] = h4;
  *(ushort4v*)&l[i4] = l4;
}

__global__ __launch_bounds__(256) void k_hist(const int* __restrict__ ei, int* __restrict__ deg,
                                              int E) {
  int e = blockIdx.x * 256 + threadIdx.x;
  if (e < E) atomicAdd(&deg[ei[E + e]], 1);
}

__global__ __launch_bounds__(1024) void k_scan(const int* __restrict__ deg, int* __restrict__ rs,
                                               int n) {
  __shared__ int wsum[16];
  __shared__ int carry;
  int tid = threadIdx.x, lane = tid & 63, wv = tid >> 6;
  if (tid == 0) carry = 0;
  __syncthreads();
  for (int base = 0; base < n; base += 1024) {
    int i = base + tid;
    int v = (i < n) ? deg[i] : 0;
    int s = v;
    #pragma unroll
    for (int o = 1; o < 64; o <<= 1) {
      int t = __shfl(s, lane - o);
      if (lane >= o) s += t;
    }
    if (lane == 63) wsum[wv] = s;
    __syncthreads();
    if (wv == 0) {
      int x = (lane < 16) ? wsum[lane] : 0;
      #pragma unroll
      for (int o = 1; o < 16; o <<= 1) {
        int t = __shfl(x, lane - o);
        if (lane >= o) x += t;
      }
      if (lane < 16) wsum[lane] = x;
    }
    __syncthreads();
    int woff = carry + (wv ? wsum[wv - 1] : 0);
    if (i < n) rs[i] = woff + s - v;
    __syncthreads();
    if (tid == 0) carry += wsum[15];
    __syncthreads();
  }
  if (tid == 0) rs[n] = carry;
}

__global__ __launch_bounds__(256) void k_scatter(const int* __restrict__ ei,
                                                 const int* __restrict__ rs,
                                                 int* __restrict__ cnt,
                                                 int* __restrict__ csr_src,
                                                 int* __restrict__ csr_dst, int E) {
  int e = blockIdx.x * 256 + threadIdx.x;
  if (e < E) {
    int d = ei[E + e];
    int p = atomicAdd(&cnt[d], 1);
    int slot = rs[d] + p;
    csr_src[slot] = ei[e];
    csr_dst[slot] = d;
  }
}

// ---------------- one-shot weight prep: transpose + hi/lo bf16 split ----------------
struct SplitJob {
  const float* W;
  const float* aux;          // b1 for type 1
  unsigned short* Th;
  unsigned short* Tl;
  float* bias_out;           // type 1 only
  int K, N, kshift, type;    // type 0: WT split; type 1: edgeconv combined W1
};
struct SplitJobs { SplitJob j[7]; };

__global__ __launch_bounds__(256) void k_prep_all(SplitJobs jobs) {
  SplitJob jb = jobs.j[blockIdx.y];
  int idx = blockIdx.x * 256 + threadIdx.x;
  if (idx >= jb.K * jb.N) return;
  float v;
  if (jb.type == 0) {
    int n = idx >> jb.kshift;
    int k = idx & (jb.K - 1);
    v = jb.W[k * jb.N + n];
  } else {
    int n = idx >> 7;
    int k = idx & 127;
    if (n < 128) v = jb.W[k * 128 + n] - jb.W[(k + 128) * 128 + n];
    else         v = jb.W[(k + 128) * 128 + (n - 128)];
    if (idx < 256) jb.bias_out[idx] = (idx < 128) ? jb.aux[idx] : 0.f;
  }
  unsigned short h = bf16_rn(v);
  jb.Th[idx] = h;
  jb.Tl[idx] = bf16_rn(v - bf16_to_f(h));
}

// ---------------- zero-LDS MFMA split-bf16 GEMM ----------------
// C[M][256] = (Ah+Al)[M][K] @ (Bh+Bl)^T (+bias); 3-term split product.
// A pre-split bf16 hi/lo [M][K]; BT pre-split [256][K].
// Block 256 thr = 4 waves; tile 64 rows x 128 cols; grid (ceil(M/64), 2).
// Wave w covers cols bn + w*32 .. +31. All fragments loaded DIRECT from
// global (A slice shared by 4 waves via L1; B shared by all blocks via L2).
// No __syncthreads in the k-loop.
__global__ __launch_bounds__(256) void k_gemm_mfma(const unsigned short* __restrict__ Ah,
                                                   const unsigned short* __restrict__ Al,
                                                   const unsigned short* __restrict__ BTh,
                                                   const unsigned short* __restrict__ BTl,
                                                   const float* __restrict__ bias,
                                                   float* __restrict__ C, int M, int K,
                                                   unsigned short* __restrict__ Ch,
                                                   unsigned short* __restrict__ Cl,
                                                   const float* __restrict__ a_s,
                                                   const float* __restrict__ a_d,
                                                   float* __restrict__ al_out) {
  __shared__ float alS[64][2];
  const int tid = threadIdx.x;
  const int bm = blockIdx.x * 64;
  const int bn = blockIdx.y * 128;
  const int w = tid >> 6, lane = tid & 63, quad = lane >> 4, lr = lane & 15;
  float4v zero4 = {0.f, 0.f, 0.f, 0.f};
  float4v acc[4][2];
  #pragma unroll
  for (int mt = 0; mt < 4; ++mt)
    #pragma unroll
    for (int nt = 0; nt < 2; ++nt) acc[mt][nt] = zero4;

  // clamped row bases (garbage rows only affect masked-out output rows)
  size_t aoff[4];
  #pragma unroll
  for (int mt = 0; mt < 4; ++mt) {
    int m = bm + mt * 16 + lr;
    aoff[mt] = (size_t)min(m, M - 1) * K;
  }
  size_t boff[2];
  #pragma unroll
  for (int nt = 0; nt < 2; ++nt) boff[nt] = (size_t)(bn + w * 32 + nt * 16 + lr) * K;

  #pragma unroll 4
  for (int k0 = 0; k0 < K; k0 += 32) {
    const int kq = k0 + quad * 8;
    short8 ah[4], alo[4], bh[2], blo[2];
    #pragma unroll
    for (int mt = 0; mt < 4; ++mt) {
      ah[mt]  = *(const short8*)&Ah[aoff[mt] + kq];
      alo[mt] = *(const short8*)&Al[aoff[mt] + kq];
    }
    #pragma unroll
    for (int nt = 0; nt < 2; ++nt) {
      bh[nt]  = *(const short8*)&BTh[boff[nt] + kq];
      blo[nt] = *(const short8*)&BTl[boff[nt] + kq];
    }
    #pragma unroll
    for (int mt = 0; mt < 4; ++mt)
      #pragma unroll
      for (int nt = 0; nt < 2; ++nt) {
        acc[mt][nt] = __builtin_amdgcn_mfma_f32_16x16x32_bf16(ah[mt], bh[nt], acc[mt][nt], 0, 0, 0);
        acc[mt][nt] = __builtin_amdgcn_mfma_f32_16x16x32_bf16(alo[mt], bh[nt], acc[mt][nt], 0, 0, 0);
        acc[mt][nt] = __builtin_amdgcn_mfma_f32_16x16x32_bf16(ah[mt], blo[nt], acc[mt][nt], 0, 0, 0);
      }
  }
  // ---- C store (layout col=lane&15, row=quad*4+reg) ----
  #pragma unroll
  for (int nt = 0; nt < 2; ++nt) {
    int n = bn + w * 32 + nt * 16 + lr;
    float bv = bias ? bias[n] : 0.f;
    #pragma unroll
    for (int mt = 0; mt < 4; ++mt) {
      #pragma unroll
      for (int r = 0; r < 4; ++r) {
        int m = bm + mt * 16 + quad * 4 + r;
        if (m < M) {
          float v = acc[mt][nt][r] + bv;
          size_t idx = (size_t)m * 256 + n;
          C[idx] = v;
          if (Ch) {
            unsigned short h = bf16_rn(v);
            Ch[idx] = h;
            Cl[idx] = bf16_rn(v - bf16_to_f(h));
          }
        }
      }
    }
  }
  // ---- fused attention logits ----
  if (a_s) {
    if (tid < 128) ((float*)alS)[tid] = 0.f;
    __syncthreads();
    float asv[2], adv[2];
    #pragma unroll
    for (int nt = 0; nt < 2; ++nt) {
      int n = bn + w * 32 + nt * 16 + lr;
      asv[nt] = a_s[n];
      adv[nt] = a_d[n];
    }
    #pragma unroll
    for (int mt = 0; mt < 4; ++mt) {
      #pragma unroll
      for (int r = 0; r < 4; ++r) {
        float ps = acc[mt][0][r] * asv[0] + acc[mt][1][r] * asv[1];
        float pd = acc[mt][0][r] * adv[0] + acc[mt][1][r] * adv[1];
        #pragma unroll
        for (int o = 8; o; o >>= 1) {
          ps += __shfl_xor(ps, o);
          pd += __shfl_xor(pd, o);
        }
        if (lr == 0) {
          int row = mt * 16 + quad * 4 + r;
          atomicAdd(&alS[row][0], ps);
          atomicAdd(&alS[row][1], pd);
        }
      }
    }
    __syncthreads();
    int head = bn >> 7;
    if (tid < 64) {
      int m = bm + tid;
      if (m < M) {
        al_out[m * 4 + head]     = alS[tid][0];
        al_out[m * 4 + 2 + head] = alS[tid][1];
      }
    }
  }
}

// ---------------- EdgeConv: P=relu(u[dst]+v[src]); H2=P@W2+b2; segment-max ----------------
__global__ __launch_bounds__(256, 4) void k_edgeconv2(const float* __restrict__ uv,
                                                      const int* __restrict__ csr_src,
                                                      const int* __restrict__ csr_dst,
                                                      const unsigned short* __restrict__ w2Th,
                                                      const unsigned short* __restrict__ w2Tl,
                                                      const float* __restrict__ b2,
                                                      float* __restrict__ x0, int E) {
  __shared__ __align__(16) char smem[34816];
  unsigned short (*Ph)[136] = (unsigned short(*)[136])smem;            // 17408 B
  unsigned short (*Pl)[136] = (unsigned short(*)[136])(smem + 17408);  // 17408 B
  float (*H2)[132] = (float(*)[132])smem;                              // alias, 33792 B
  __shared__ int sSrc[64], sDst[64];

  const int tid = threadIdx.x;
  const int e0 = blockIdx.x * 64;
  const int w = tid >> 6, lane = tid & 63, quad = lane >> 4, lr = lane & 15;
  if (tid < 64) {
    int e = e0 + tid;
    sSrc[tid] = (e < E) ? csr_src[e] : -1;
    sDst[tid] = (e < E) ? csr_dst[e] : -1;
  }
  __syncthreads();
  #pragma unroll
  for (int c = tid; c < 1024; c += 256) {
    int r = c >> 4;
    int kq = (c & 15) * 8;
    float pv[8];
    int sn = sSrc[r], dn = sDst[r];
    if (sn >= 0) {
      float4 u0 = *(const float4*)&uv[(size_t)dn * 256 + kq];
      float4 u1 = *(const float4*)&uv[(size_t)dn * 256 + kq + 4];
      float4 v0 = *(const float4*)&uv[(size_t)sn * 256 + 128 + kq];
      float4 v1 = *(const float4*)&uv[(size_t)sn * 256 + 128 + kq + 4];
      pv[0] = fmaxf(u0.x + v0.x, 0.f); pv[1] = fmaxf(u0.y + v0.y, 0.f);
      pv[2] = fmaxf(u0.z + v0.z, 0.f); pv[3] = fmaxf(u0.w + v0.w, 0.f);
      pv[4] = fmaxf(u1.x + v1.x, 0.f); pv[5] = fmaxf(u1.y + v1.y, 0.f);
      pv[6] = fmaxf(u1.z + v1.z, 0.f); pv[7] = fmaxf(u1.w + v1.w, 0.f);
    } else {
      #pragma unroll
      for (int i = 0; i < 8; ++i) pv[i] = 0.f;
    }
    short8 h8, l8;
    #pragma unroll
    for (int i = 0; i < 8; ++i) {
      unsigned short h = bf16_rn(pv[i]);
      h8[i] = (short)h;
      l8[i] = (short)bf16_rn(pv[i] - bf16_to_f(h));
    }
    *(short8*)&Ph[r][kq] = h8;
    *(short8*)&Pl[r][kq] = l8;
  }
  __syncthreads();
  float4v zero4 = {0.f, 0.f, 0.f, 0.f};
  float4v acc[4][2];
  #pragma unroll
  for (int mt = 0; mt < 4; ++mt)
    #pragma unroll
    for (int nt = 0; nt < 2; ++nt) acc[mt][nt] = zero4;

  #pragma unroll
  for (int k0 = 0; k0 < 128; k0 += 32) {
    short8 ah[4], alo[4], bh[2], blo[2];
    #pragma unroll
    for (int nt = 0; nt < 2; ++nt) {
      int n = w * 32 + nt * 16 + lr;
      bh[nt]  = *(const short8*)&w2Th[(size_t)n * 128 + k0 + quad * 8];
      blo[nt] = *(const short8*)&w2Tl[(size_t)n * 128 + k0 + quad * 8];
    }
    #pragma unroll
    for (int mt = 0; mt < 4; ++mt) {
      ah[mt]  = *(short8*)&Ph[mt * 16 + lr][k0 + quad * 8];
      alo[mt] = *(short8*)&Pl[mt * 16 + lr][k0 + quad * 8];
    }
    #pragma unroll
    for (int mt = 0; mt < 4; ++mt)
      #pragma unroll
      for (int nt = 0; nt < 2; ++nt) {
        acc[mt][nt] = __builtin_amdgcn_mfma_f32_16x16x32_bf16(ah[mt], bh[nt], acc[mt][nt], 0, 0, 0);
        acc[mt][nt] = __builtin_amdgcn_mfma_f32_16x16x32_bf16(alo[mt], bh[nt], acc[mt][nt], 0, 0, 0);
        acc[mt][nt] = __builtin_amdgcn_mfma_f32_16x16x32_bf16(ah[mt], blo[nt], acc[mt][nt], 0, 0, 0);
      }
  }
  __syncthreads();  // P dead; reuse as H2
  #pragma unroll
  for (int nt = 0; nt < 2; ++nt) {
    int n = w * 32 + nt * 16 + lr;
    float bv = b2[n];
    #pragma unroll
    for (int mt = 0; mt < 4; ++mt) {
      #pragma unroll
      for (int r = 0; r < 4; ++r) {
        int row = mt * 16 + quad * 4 + r;
        H2[row][n] = acc[mt][nt][r] + bv;
      }
    }
  }
  __syncthreads();
  if (tid < 128) {
    int col = tid;
    int prev = sDst[0];
    float rmax = H2[0][col];
    for (int r = 1; r < 64; ++r) {
      int d = sDst[r];
      float v = H2[r][col];
      if (d == prev) {
        rmax = fmaxf(rmax, v);
      } else {
        if (prev >= 0) atomicMaxF(&x0[(size_t)prev * 128 + col], rmax);
        prev = d;
        rmax = v;
      }
    }
    if (prev >= 0) atomicMaxF(&x0[(size_t)prev * 128 + col], rmax);
  }
}

// ---------------- GAT segment softmax + aggregation, one wave per node ----------------
__global__ __launch_bounds__(256) void k_gat_agg(const float* __restrict__ Hf,
                                                 const float* __restrict__ al,
                                                 const int* __restrict__ rs,
                                                 const int* __restrict__ csr_src,
                                                 const float* __restrict__ bias,
                                                 const float* __restrict__ res,
                                                 float* __restrict__ out,
                                                 unsigned short* __restrict__ outh,
                                                 unsigned short* __restrict__ outl, int N) {
  int wave = threadIdx.x >> 6, lane = threadIdx.x & 63;
  int i = blockIdx.x * 4 + wave;
  if (i >= N) return;
  int beg = rs[i], end = rs[i + 1];
  int deg = end - beg;
  float4 me = *(const float4*)&al[i * 4];
  float ad0 = me.z, ad1 = me.w;
  float sl0 = leaky(me.x + ad0);
  float sl1 = leaky(me.y + ad1);
  const int c = lane << 2;
  const int hsel = lane >> 5;
  float a0, a1, a2, a3;

  if (deg <= 64) {
    int s = 0;
    float l0 = -INFINITY, l1 = -INFINITY;
    bool act = lane < deg;
    if (act) {
      s = csr_src[beg + lane];
      float4 a4 = *(const float4*)&al[s * 4];
      l0 = leaky(a4.x + ad0);
      l1 = leaky(a4.y + ad1);
    }
    float m0 = fmaxf(sl0, l0), m1 = fmaxf(sl1, l1);
    #pragma unroll
    for (int o = 32; o; o >>= 1) {
      m0 = fmaxf(m0, __shfl_xor(m0, o));
      m1 = fmaxf(m1, __shfl_xor(m1, o));
    }
    float w0 = act ? __expf(l0 - m0) : 0.f;
    float w1 = act ? __expf(l1 - m1) : 0.f;
    float s0 = w0, s1 = w1;
    #pragma unroll
    for (int o = 32; o; o >>= 1) {
      s0 += __shfl_xor(s0, o);
      s1 += __shfl_xor(s1, o);
    }
    s0 += __expf(sl0 - m0);
    s1 += __expf(sl1 - m1);
    float inv0 = 1.f / (s0 + 1e-16f), inv1 = 1.f / (s1 + 1e-16f);
    float wp0 = w0 * inv0, wp1 = w1 * inv1;
    float wself = hsel ? __expf(sl1 - m1) * inv1 : __expf(sl0 - m0) * inv0;
    float4 hv = *(const float4*)&Hf[(size_t)i * 256 + c];
    a0 = wself * hv.x; a1 = wself * hv.y; a2 = wself * hv.z; a3 = wself * hv.w;
    float b0 = 0.f, b1 = 0.f, b2 = 0.f, b3 = 0.f;
    float c0 = 0.f, c1 = 0.f, c2 = 0.f, c3 = 0.f;
    float d0 = 0.f, d1 = 0.f, d2 = 0.f, d3 = 0.f;
    int j = 0;
    for (; j + 4 <= deg; j += 4) {
      int s_0 = __shfl(s, j);     float wA0 = __shfl(wp0, j);     float wB0 = __shfl(wp1, j);
      int s_1 = __shfl(s, j + 1); float wA1 = __shfl(wp0, j + 1); float wB1 = __shfl(wp1, j + 1);
      int s_2 = __shfl(s, j + 2); float wA2 = __shfl(wp0, j + 2); float wB2 = __shfl(wp1, j + 2);
      int s_3 = __shfl(s, j + 3); float wA3 = __shfl(wp0, j + 3); float wB3 = __shfl(wp1, j + 3);
      float4 h0 = *(const float4*)&Hf[(size_t)s_0 * 256 + c];
      float4 h1 = *(const float4*)&Hf[(size_t)s_1 * 256 + c];
      float4 h2 = *(const float4*)&Hf[(size_t)s_2 * 256 + c];
      float4 h3 = *(const float4*)&Hf[(size_t)s_3 * 256 + c];
      float w_0 = hsel ? wB0 : wA0;
      float w_1 = hsel ? wB1 : wA1;
      float w_2 = hsel ? wB2 : wA2;
      float w_3 = hsel ? wB3 : wA3;
      a0 += w_0 * h0.x; a1 += w_0 * h0.y; a2 += w_0 * h0.z; a3 += w_0 * h0.w;
      b0 += w_1 * h1.x; b1 += w_1 * h1.y; b2 += w_1 * h1.z; b3 += w_1 * h1.w;
      c0 += w_2 * h2.x; c1 += w_2 * h2.y; c2 += w_2 * h2.z; c3 += w_2 * h2.w;
      d0 += w_3 * h3.x; d1 += w_3 * h3.y; d2 += w_3 * h3.z; d3 += w_3 * h3.w;
    }
    for (; j < deg; ++j) {
      int sj = __shfl(s, j);
      float wA = __shfl(wp0, j), wB = __shfl(wp1, j);
      float wj = hsel ? wB : wA;
      float4 h4 = *(const float4*)&Hf[(size_t)sj * 256 + c];
      a0 += wj * h4.x; a1 += wj * h4.y; a2 += wj * h4.z; a3 += wj * h4.w;
    }
    a0 += b0 + c0 + d0; a1 += b1 + c1 + d1;
    a2 += b2 + c2 + d2; a3 += b3 + c3 + d3;
  } else {
    float m0 = sl0, m1 = sl1;
    for (int e = beg + lane; e < end; e += 64) {
      int s = csr_src[e];
      m0 = fmaxf(m0, leaky(al[s * 4 + 0] + ad0));
      m1 = fmaxf(m1, leaky(al[s * 4 + 1] + ad1));
    }
    #pragma unroll
    for (int o = 32; o; o >>= 1) {
      m0 = fmaxf(m0, __shfl_xor(m0, o));
      m1 = fmaxf(m1, __shfl_xor(m1, o));
    }
    float s0 = 0.f, s1 = 0.f;
    for (int e = beg + lane; e < end; e += 64) {
      int s = csr_src[e];
      s0 += __expf(leaky(al[s * 4 + 0] + ad0) - m0);
      s1 += __expf(leaky(al[s * 4 + 1] + ad1) - m1);
    }
    #pragma unroll
    for (int o = 32; o; o >>= 1) {
      s0 += __shfl_xor(s0, o);
      s1 += __shfl_xor(s1, o);
    }
    s0 += __expf(sl0 - m0);
    s1 += __expf(sl1 - m1);
    float inv0 = 1.f / (s0 + 1e-16f), inv1 = 1.f / (s1 + 1e-16f);
    float mh = hsel ? m1 : m0;
    float invh = hsel ? inv1 : inv0;
    float adh = hsel ? ad1 : ad0;
    float wself = __expf((hsel ? sl1 : sl0) - mh) * invh;
    float4 hv = *(const float4*)&Hf[(size_t)i * 256 + c];
    a0 = wself * hv.x; a1 = wself * hv.y; a2 = wself * hv.z; a3 = wself * hv.w;
    for (int e = beg; e < end; ++e) {
      int s = csr_src[e];
      float wgt = __expf(leaky(al[s * 4 + hsel] + adh) - mh) * invh;
      float4 h4 = *(const float4*)&Hf[(size_t)s * 256 + c];
      a0 += wgt * h4.x; a1 += wgt * h4.y; a2 += wgt * h4.z; a3 += wgt * h4.w;
    }
  }
  float4 bv = *(const float4*)&bias[c];
  float4 o4;
  o4.x = fmaxf(a0 + bv.x, 0.f);
  o4.y = fmaxf(a1 + bv.y, 0.f);
  o4.z = fmaxf(a2 + bv.z, 0.f);
  o4.w = fmaxf(a3 + bv.w, 0.f);
  if (res) {
    float4 r4 = *(const float4*)&res[(size_t)i * 256 + c];
    o4.x += r4.x; o4.y += r4.y; o4.z += r4.z; o4.w += r4.w;
  }
  size_t idx = (size_t)i * 256 + c;
  *(float4*)&out[idx] = o4;
  if (outh) {
    unsigned short hx = bf16_rn(o4.x), hy = bf16_rn(o4.y), hz = bf16_rn(o4.z), hw = bf16_rn(o4.w);
    ushort4v h4 = {hx, hy, hz, hw};
    ushort4v l4 = {bf16_rn(o4.x - bf16_to_f(hx)), bf16_rn(o4.y - bf16_to_f(hy)),
                   bf16_rn(o4.z - bf16_to_f(hz)), bf16_rn(o4.w - bf16_to_f(hw))};
    *(ushort4v*)&outh[idx] = h4;
    *(ushort4v*)&outl[idx] = l4;
  }
}

// ---------------- final projection ----------------
__global__ __launch_bounds__(256) void k_findot(const float* __restrict__ X,
                                                const float* __restrict__ fw,
                                                const float* __restrict__ fb,
                                                float* __restrict__ out, int N) {
  int wave = threadIdx.x >> 6, lane = threadIdx.x & 63;
  int i = blockIdx.x * 4 + wave;
  if (i >= N) return;
  float4 xv = *(const float4*)&X[(size_t)i * 256 + (lane << 2)];
  float4 wv = *(const float4*)&fw[lane << 2];
  float p = xv.x * wv.x + xv.y * wv.y + xv.z * wv.z + xv.w * wv.w;
  #pragma unroll
  for (int o = 32; o; o >>= 1) p += __shfl_xor(p, o);
  if (lane == 0) out[i] = p + fb[0];
}

// ---------------------------------------------------------------------------
extern "C" void kernel_launch(void* const* d_in, const int* in_sizes, int n_in,
                              void* d_out, int out_size, void* d_ws, size_t ws_size,
                              hipStream_t stream) {
  const float* x      = (const float*)d_in[0];
  const int*   ei     = (const int*)d_in[1];
  const float* ec_w1  = (const float*)d_in[3];
  const float* ec_b1  = (const float*)d_in[4];
  const float* ec_w2  = (const float*)d_in[5];
  const float* ec_b2  = (const float*)d_in[6];
  const float* reg_w  = (const float*)d_in[7];
  const float* reg_b  = (const float*)d_in[8];
  const float* fin_w  = (const float*)d_in[9];
  const float* fin_b  = (const float*)d_in[10];
  const float* g1_w   = (const float*)d_in[11];
  const float* g1_as  = (const float*)d_in[12];
  const float* g1_ad  = (const float*)d_in[13];
  const float* g1_b   = (const float*)d_in[14];
  const float* g2_w   = (const float*)d_in[15];
  const float* g2_as  = (const float*)d_in[16];
  const float* g2_ad  = (const float*)d_in[17];
  const float* g2_b   = (const float*)d_in[18];
  const float* g3_w   = (const float*)d_in[19];
  const float* g3_as  = (const float*)d_in[20];
  const float* g3_ad  = (const float*)d_in[21];
  const float* g3_b   = (const float*)d_in[22];
  const float* g4_w   = (const float*)d_in[23];
  const float* g4_as  = (const float*)d_in[24];
  const float* g4_ad  = (const float*)d_in[25];
  const float* g4_b   = (const float*)d_in[26];

  const int N = in_sizes[0] / 128;
  const int E = in_sizes[1] / 2;

  char* base = (char*)d_ws;
  size_t off = 0;
  auto alloc = [&](size_t bytes) -> char* {
    char* p = base + off;
    off += (bytes + 255) & ~(size_t)255;
    return p;
  };
  const size_t szN4 = ((size_t)N * 4 + 255) & ~(size_t)255;
  int*   deg      = (int*)alloc((size_t)N * 4);
  int*   cnt      = (int*)alloc((size_t)N * 4);
  int*   rs       = (int*)alloc((size_t)(N + 1) * 4);
  int*   csr_src  = (int*)alloc((size_t)E * 4);
  int*   csr_dst  = (int*)alloc((size_t)E * 4);
  float* bias_cat = (float*)alloc(256 * 4);
  unsigned short* bcatTh = (unsigned short*)alloc(256 * 128 * 2);
  unsigned short* bcatTl = (unsigned short*)alloc(256 * 128 * 2);
  unsigned short* w2Th   = (unsigned short*)alloc(128 * 128 * 2);
  unsigned short* w2Tl   = (unsigned short*)alloc(128 * 128 * 2);
  unsigned short* g1Th   = (unsigned short*)alloc(256 * 128 * 2);
  unsigned short* g1Tl   = (unsigned short*)alloc(256 * 128 * 2);
  unsigned short* g2Th   = (unsigned short*)alloc(256 * 256 * 2);
  unsigned short* g2Tl   = (unsigned short*)alloc(256 * 256 * 2);
  unsigned short* g3Th   = (unsigned short*)alloc(256 * 256 * 2);
  unsigned short* g3Tl   = (unsigned short*)alloc(256 * 256 * 2);
  unsigned short* g4Th   = (unsigned short*)alloc(256 * 256 * 2);
  unsigned short* g4Tl   = (unsigned short*)alloc(256 * 256 * 2);
  unsigned short* regTh  = (unsigned short*)alloc(256 * 256 * 2);
  unsigned short* regTl  = (unsigned short*)alloc(256 * 256 * 2);
  float* uv = (float*)alloc((size_t)N * 256 * 4);
  float* x0 = (float*)alloc((size_t)N * 128 * 4);
  float* X1 = (float*)alloc((size_t)N * 256 * 4);
  float* X2 = (float*)alloc((size_t)N * 256 * 4);
  float* al = (float*)alloc((size_t)N * 4 * 4);
  // ping-pong split-activation buffers (N x 256 bf16 hi/lo each)
  unsigned short* s1h = (unsigned short*)alloc((size_t)N * 256 * 2);
  unsigned short* s1l = (unsigned short*)alloc((size_t)N * 256 * 2);
  unsigned short* s2h = (unsigned short*)alloc((size_t)N * 256 * 2);
  unsigned short* s2l = (unsigned short*)alloc((size_t)N * 256 * 2);
  (void)ws_size; (void)n_in; (void)out_size;

  const int nodeWaveBlocks = (N + 3) / 4;
  const dim3 gemmGrid((N + 63) / 64, 2);
  const int splitBlocks128 = (N * 128 / 4 + 255) / 256;

  // --- weight prep (one launch for all transposes/splits) ---
  SplitJobs jobs;
  jobs.j[0] = {ec_w2, nullptr, w2Th, w2Tl, nullptr, 128, 128, 7, 0};
  jobs.j[1] = {g1_w,  nullptr, g1Th, g1Tl, nullptr, 128, 256, 7, 0};
  jobs.j[2] = {g2_w,  nullptr, g2Th, g2Tl, nullptr, 256, 256, 8, 0};
  jobs.j[3] = {g3_w,  nullptr, g3Th, g3Tl, nullptr, 256, 256, 8, 0};
  jobs.j[4] = {g4_w,  nullptr, g4Th, g4Tl, nullptr, 256, 256, 8, 0};
  jobs.j[5] = {reg_w, nullptr, regTh, regTl, nullptr, 256, 256, 8, 0};
  jobs.j[6] = {ec_w1, ec_b1, bcatTh, bcatTl, bias_cat, 128, 256, 7, 1};
  k_prep_all<<<dim3(256, 7), 256, 0, stream>>>(jobs);

  // --- CSR build ---
  hipMemsetAsync(deg, 0, 2 * szN4, stream);  // deg + cnt are adjacent
  k_hist<<<(E + 255) / 256, 256, 0, stream>>>(ei, deg, E);
  k_scan<<<1, 1024, 0, stream>>>(deg, rs, N);
  k_scatter<<<(E + 255) / 256, 256, 0, stream>>>(ei, rs, cnt, csr_src, csr_dst, E);

  // --- EdgeConv ---
  k_split_act<<<splitBlocks128, 256, 0, stream>>>(x, s1h, s1l, N * 128, 0);
  k_gemm_mfma<<<gemmGrid, 256, 0, stream>>>(s1h, s1l, bcatTh, bcatTl, bias_cat, uv, N, 128,
                                            nullptr, nullptr, nullptr, nullptr, nullptr);
  k_fill_f32<<<(N * 128 + 255) / 256, 256, 0, stream>>>(x0, -INFINITY, N * 128);
  k_edgeconv2<<<(E + 63) / 64, 256, 0, stream>>>(uv, csr_src, csr_dst, w2Th, w2Tl, ec_b2, x0, E);
  k_split_act<<<splitBlocks128, 256, 0, stream>>>(x0, s1h, s1l, N * 128, 1);

  // --- GAT1: X1 = relu(gat(x0)) ---
  k_gemm_mfma<<<gemmGrid, 256, 0, stream>>>(s1h, s1l, g1Th, g1Tl, nullptr, uv, N, 128,
                                            nullptr, nullptr, g1_as, g1_ad, al);
  k_gat_agg<<<nodeWaveBlocks, 256, 0, stream>>>(uv, al, rs, csr_src, g1_b, nullptr, X1,
                                                s1h, s1l, N);

  // --- GAT2: X2 = relu(gat(X1)) + X1 ---
  k_gemm_mfma<<<gemmGrid, 256, 0, stream>>>(s1h, s1l, g2Th, g2Tl, nullptr, uv, N, 256,
                                            nullptr, nullptr, g2_as, g2_ad, al);
  k_gat_agg<<<nodeWaveBlocks, 256, 0, stream>>>(uv, al, rs, csr_src, g2_b, X1, X2,
                                                s2h, s2l, N);

  // --- reg: X1 = X2 @ reg_w + reg_b (fp32 + split) ---
  k_gemm_mfma<<<gemmGrid, 256, 0, stream>>>(s2h, s2l, regTh, regTl, reg_b, X1, N, 256,
                                            s1h, s1l, nullptr, nullptr, nullptr);

  // --- GAT3: X2 = relu(gat(X1)) + X1 ---
  k_gemm_mfma<<<gemmGrid, 256, 0, stream>>>(s1h, s1l, g3Th, g3Tl, nullptr, uv, N, 256,
                                            nullptr, nullptr, g3_as, g3_ad, al);
  k_gat_agg<<<nodeWaveBlocks, 256, 0, stream>>>(uv, al, rs, csr_src, g3_b, X1, X2,
                                                s2h, s2l, N);

  // --- GAT4: X1 = relu(gat(X2)) ---
  k_gemm_mfma<<<gemmGrid, 256, 0, stream>>>(s2h, s2l, g4Th, g4Tl, nullptr, uv, N, 256,
                                            nullptr, nullptr, g4_as, g4_ad, al);
  k_gat_agg<<<nodeWaveBlocks, 256, 0, stream>>>(uv, al, rs, csr_src, g4_b, nullptr, X1,
                                                nullptr, nullptr, N);

  // --- final linear ---
  k_findot<<<nodeWaveBlocks, 256, 0, stream>>>(X1, fin_w, fin_b, (float*)d_out, N);
}

// Round 5
// 642.830 us; speedup vs baseline: 1.0824x; 1.0824x over previous
//
#include <hip/hip_runtime.h>
#include <math.h>

// ---------------------------------------------------------------------------
// SymmetricalResidualGAT: EdgeConv(max) + GAT x4 (H=2, C=128) + linears.
// N=20000, E=320000. Round 5: GEMM = 128x128 tile, fragment-order LDS staged
// via global_load_lds (16B), pre-split bf16 hi/lo operands, 3-term MFMA.
// ---------------------------------------------------------------------------

#define NEG_SLOPE 0.2f

typedef short short8 __attribute__((ext_vector_type(8)));
typedef float float4v __attribute__((ext_vector_type(4)));
typedef unsigned short ushort4v __attribute__((ext_vector_type(4)));

#define AS1 __attribute__((address_space(1)))
#define AS3 __attribute__((address_space(3)))

__device__ __forceinline__ void cp16(const void* g, void* l) {
  // async global->LDS, 16B/lane; LDS dest = wave-uniform base + lane*16
  __builtin_amdgcn_global_load_lds((const AS1 unsigned int*)g, (AS3 unsigned int*)l, 16, 0, 0);
}

__device__ __forceinline__ float leaky(float x) { return x > 0.f ? x : NEG_SLOPE * x; }

__device__ __forceinline__ void atomicMaxF(float* addr, float v) {
  if (v >= 0.f) atomicMax((int*)addr, __float_as_int(v));
  else          atomicMin((unsigned int*)addr, __float_as_uint(v));
}

__device__ __forceinline__ unsigned short bf16_rn(float f) {
  unsigned u = __float_as_uint(f);
  unsigned r = (u + 0x7FFFu + ((u >> 16) & 1u)) >> 16;
  return (unsigned short)r;
}
__device__ __forceinline__ float bf16_to_f(unsigned short h) {
  return __uint_as_float(((unsigned)h) << 16);
}

// ---------------- small kernels ----------------
__global__ __launch_bounds__(256) void k_fill_f32(float* p, float v, int n) {
  int i = blockIdx.x * 256 + threadIdx.x;
  if (i < n) p[i] = v;
}

__global__ __launch_bounds__(256) void k_split_act(const float* __restrict__ src,
                                                   unsigned short* __restrict__ h,
                                                   unsigned short* __restrict__ l,
                                                   int n, int fixinf) {
  int i4 = (blockIdx.x * 256 + threadIdx.x) * 4;
  if (i4 >= n) return;
  float4 v = *(const float4*)&src[i4];
  if (fixinf) {
    if (v.x == -INFINITY) v.x = 0.f;
    if (v.y == -INFINITY) v.y = 0.f;
    if (v.z == -INFINITY) v.z = 0.f;
    if (v.w == -INFINITY) v.w = 0.f;
  }
  unsigned short hx = bf16_rn(v.x), hy = bf16_rn(v.y), hz = bf16_rn(v.z), hw = bf16_rn(v.w);
  ushort4v h4 = {hx, hy, hz, hw};
  ushort4v l4 = {bf16_rn(v.x - bf16_to_f(hx)), bf16_rn(v.y - bf16_to_f(hy)),
                 bf16_rn(v.z - bf16_to_f(hz)), bf16_rn(v.w - bf16_to_f(hw))};
  *(ushort4v*)&h[i4] = h4;
  *(ushort4v*)&l[i4] = l4;
}

__global__ __launch_bounds__(256) void k_hist(const int* __restrict__ ei, int* __restrict__ deg,
                                              int E) {
  int e = blockIdx.x * 256 + threadIdx.x;
  if (e < E) atomicAdd(&deg[ei[E + e]], 1);
}

__global__ __launch_bounds__(1024) void k_scan(const int* __restrict__ deg, int* __restrict__ rs,
                                               int n) {
  __shared__ int wsum[16];
  __shared__ int carry;
  int tid = threadIdx.x, lane = tid & 63, wv = tid >> 6;
  if (tid == 0) carry = 0;
  __syncthreads();
  for (int base = 0; base < n; base += 1024) {
    int i = base + tid;
    int v = (i < n) ? deg[i] : 0;
    int s = v;
    #pragma unroll
    for (int o = 1; o < 64; o <<= 1) {
      int t = __shfl(s, lane - o);
      if (lane >= o) s += t;
    }
    if (lane == 63) wsum[wv] = s;
    __syncthreads();
    if (wv == 0) {
      int x = (lane < 16) ? wsum[lane] : 0;
      #pragma unroll
      for (int o = 1; o < 16; o <<= 1) {
        int t = __shfl(x, lane - o);
        if (lane >= o) x += t;
      }
      if (lane < 16) wsum[lane] = x;
    }
    __syncthreads();
    int woff = carry + (wv ? wsum[wv - 1] : 0);
    if (i < n) rs[i] = woff + s - v;
    __syncthreads();
    if (tid == 0) carry += wsum[15];
    __syncthreads();
  }
  if (tid == 0) rs[n] = carry;
}

__global__ __launch_bounds__(256) void k_scatter(const int* __restrict__ ei,
                                                 const int* __restrict__ rs,
                                                 int* __restrict__ cnt,
                                                 int* __restrict__ csr_src,
                                                 int* __restrict__ csr_dst, int E) {
  int e = blockIdx.x * 256 + threadIdx.x;
  if (e < E) {
    int d = ei[E + e];
    int p = atomicAdd(&cnt[d], 1);
    int slot = rs[d] + p;
    csr_src[slot] = ei[e];
    csr_dst[slot] = d;
  }
}

// ---------------- one-shot weight prep: transpose + hi/lo bf16 split ----------------
struct SplitJob {
  const float* W;
  const float* aux;
  unsigned short* Th;
  unsigned short* Tl;
  float* bias_out;
  int K, N, kshift, type;
};
struct SplitJobs { SplitJob j[7]; };

__global__ __launch_bounds__(256) void k_prep_all(SplitJobs jobs) {
  SplitJob jb = jobs.j[blockIdx.y];
  int idx = blockIdx.x * 256 + threadIdx.x;
  if (idx >= jb.K * jb.N) return;
  float v;
  if (jb.type == 0) {
    int n = idx >> jb.kshift;
    int k = idx & (jb.K - 1);
    v = jb.W[k * jb.N + n];
  } else {
    int n = idx >> 7;
    int k = idx & 127;
    if (n < 128) v = jb.W[k * 128 + n] - jb.W[(k + 128) * 128 + n];
    else         v = jb.W[(k + 128) * 128 + (n - 128)];
    if (idx < 256) jb.bias_out[idx] = (idx < 128) ? jb.aux[idx] : 0.f;
  }
  unsigned short h = bf16_rn(v);
  jb.Th[idx] = h;
  jb.Tl[idx] = bf16_rn(v - bf16_to_f(h));
}

// ---------------- MFMA split-bf16 GEMM, 128x128 tile, LDS fragment-order ----------------
// C[M][256] = (Ah+Al)[M][K] @ (BTh+BTl)[256][K]^T (+bias).
// 256 thr = 4 waves (2x2); wave covers 64x64 via 4x4 16x16 tiles.
// LDS: A/B tiles in fragment order (tile t, slot lane*16B), staged by
// global_load_lds 16B -> conflict-free ds_reads, no staging VALU.
__global__ __launch_bounds__(256) void k_gemm_mfma(const unsigned short* __restrict__ Ah,
                                                   const unsigned short* __restrict__ Al,
                                                   const unsigned short* __restrict__ BTh,
                                                   const unsigned short* __restrict__ BTl,
                                                   const float* __restrict__ bias,
                                                   float* __restrict__ C, int M, int K,
                                                   unsigned short* __restrict__ Ch,
                                                   unsigned short* __restrict__ Cl,
                                                   const float* __restrict__ a_s,
                                                   const float* __restrict__ a_d,
                                                   float* __restrict__ al_out) {
  __shared__ __align__(16) char sm[32768];   // AhS | AlS | BhS | BlS (8KB each)
  __shared__ float alS[128][2];
  char* AhS = sm;
  char* AlS = sm + 8192;
  char* BhS = sm + 16384;
  char* BlS = sm + 24576;

  const int tid = threadIdx.x;
  const int bm = blockIdx.x * 128;
  const int bn = blockIdx.y * 128;
  const int w = tid >> 6, lane = tid & 63, quad = lane >> 4, lr = lane & 15;
  const int wr = w >> 1, wc = w & 1;
  const int kq8 = quad * 8;

  float4v zero4 = {0.f, 0.f, 0.f, 0.f};
  float4v acc[4][4];
  #pragma unroll
  for (int mt = 0; mt < 4; ++mt)
    #pragma unroll
    for (int nt = 0; nt < 4; ++nt) acc[mt][nt] = zero4;

  // staging addresses: wave w stages A tiles {2w,2w+1} and B tiles {2w,2w+1}
  int ar0 = bm + (2 * w) * 16 + lr;     if (ar0 >= M) ar0 = M - 1;
  int ar1 = bm + (2 * w + 1) * 16 + lr; if (ar1 >= M) ar1 = M - 1;
  const size_t aoff0 = (size_t)ar0 * K + kq8;
  const size_t aoff1 = (size_t)ar1 * K + kq8;
  const size_t boff0 = (size_t)(bn + (2 * w) * 16 + lr) * K + kq8;
  const size_t boff1 = (size_t)(bn + (2 * w + 1) * 16 + lr) * K + kq8;
  char* ldsA0 = AhS + (2 * w) * 1024;
  char* ldsA1 = AhS + (2 * w + 1) * 1024;
  char* ldsAl0 = AlS + (2 * w) * 1024;
  char* ldsAl1 = AlS + (2 * w + 1) * 1024;
  char* ldsB0 = BhS + (2 * w) * 1024;
  char* ldsB1 = BhS + (2 * w + 1) * 1024;
  char* ldsBl0 = BlS + (2 * w) * 1024;
  char* ldsBl1 = BlS + (2 * w + 1) * 1024;

  for (int k0 = 0; k0 < K; k0 += 32) {
    __syncthreads();
    cp16(Ah + aoff0 + k0, ldsA0);
    cp16(Ah + aoff1 + k0, ldsA1);
    cp16(Al + aoff0 + k0, ldsAl0);
    cp16(Al + aoff1 + k0, ldsAl1);
    cp16(BTh + boff0 + k0, ldsB0);
    cp16(BTh + boff1 + k0, ldsB1);
    cp16(BTl + boff0 + k0, ldsBl0);
    cp16(BTl + boff1 + k0, ldsBl1);
    __syncthreads();   // drains vmcnt then barrier
    short8 ah[4], alo[4], bh[4], blo[4];
    #pragma unroll
    for (int mt = 0; mt < 4; ++mt) {
      int t = wr * 4 + mt;
      ah[mt]  = *(const short8*)(AhS + t * 1024 + lane * 16);
      alo[mt] = *(const short8*)(AlS + t * 1024 + lane * 16);
    }
    #pragma unroll
    for (int nt = 0; nt < 4; ++nt) {
      int t = wc * 4 + nt;
      bh[nt]  = *(const short8*)(BhS + t * 1024 + lane * 16);
      blo[nt] = *(const short8*)(BlS + t * 1024 + lane * 16);
    }
    #pragma unroll
    for (int mt = 0; mt < 4; ++mt)
      #pragma unroll
      for (int nt = 0; nt < 4; ++nt) {
        acc[mt][nt] = __builtin_amdgcn_mfma_f32_16x16x32_bf16(ah[mt], bh[nt], acc[mt][nt], 0, 0, 0);
        acc[mt][nt] = __builtin_amdgcn_mfma_f32_16x16x32_bf16(alo[mt], bh[nt], acc[mt][nt], 0, 0, 0);
        acc[mt][nt] = __builtin_amdgcn_mfma_f32_16x16x32_bf16(ah[mt], blo[nt], acc[mt][nt], 0, 0, 0);
      }
  }
  // ---- C store (layout col=lane&15, row=quad*4+reg) ----
  #pragma unroll
  for (int nt = 0; nt < 4; ++nt) {
    int n = bn + wc * 64 + nt * 16 + lr;
    float bv = bias ? bias[n] : 0.f;
    #pragma unroll
    for (int mt = 0; mt < 4; ++mt) {
      #pragma unroll
      for (int r = 0; r < 4; ++r) {
        int m = bm + wr * 64 + mt * 16 + quad * 4 + r;
        if (m < M) {
          float v = acc[mt][nt][r] + bv;
          size_t idx = (size_t)m * 256 + n;
          C[idx] = v;
          if (Ch) {
            unsigned short h = bf16_rn(v);
            Ch[idx] = h;
            Cl[idx] = bf16_rn(v - bf16_to_f(h));
          }
        }
      }
    }
  }
  // ---- fused attention logits (block y == head) ----
  if (a_s) {
    ((float*)alS)[tid] = 0.f;
    __syncthreads();
    float asv[4], adv[4];
    #pragma unroll
    for (int nt = 0; nt < 4; ++nt) {
      int n = bn + wc * 64 + nt * 16 + lr;
      asv[nt] = a_s[n];
      adv[nt] = a_d[n];
    }
    #pragma unroll
    for (int mt = 0; mt < 4; ++mt) {
      #pragma unroll
      for (int r = 0; r < 4; ++r) {
        float ps = 0.f, pd = 0.f;
        #pragma unroll
        for (int nt = 0; nt < 4; ++nt) {
          ps += acc[mt][nt][r] * asv[nt];
          pd += acc[mt][nt][r] * adv[nt];
        }
        #pragma unroll
        for (int o = 8; o; o >>= 1) {
          ps += __shfl_xor(ps, o);
          pd += __shfl_xor(pd, o);
        }
        if (lr == 0) {
          int row = wr * 64 + mt * 16 + quad * 4 + r;
          atomicAdd(&alS[row][0], ps);
          atomicAdd(&alS[row][1], pd);
        }
      }
    }
    __syncthreads();
    int head = bn >> 7;
    if (tid < 128) {
      int m = bm + tid;
      if (m < M) {
        al_out[m * 4 + head]     = alS[tid][0];
        al_out[m * 4 + 2 + head] = alS[tid][1];
      }
    }
  }
}

// ---------------- EdgeConv: P=relu(u[dst]+v[src]); H2=P@W2+b2; segment-max ----------------
__global__ __launch_bounds__(256, 4) void k_edgeconv2(const float* __restrict__ uv,
                                                      const int* __restrict__ csr_src,
                                                      const int* __restrict__ csr_dst,
                                                      const unsigned short* __restrict__ w2Th,
                                                      const unsigned short* __restrict__ w2Tl,
                                                      const float* __restrict__ b2,
                                                      float* __restrict__ x0, int E) {
  __shared__ __align__(16) char smem[34816];
  unsigned short (*Ph)[136] = (unsigned short(*)[136])smem;            // 17408 B
  unsigned short (*Pl)[136] = (unsigned short(*)[136])(smem + 17408);  // 17408 B
  float (*H2)[132] = (float(*)[132])smem;                              // alias, 33792 B
  __shared__ int sSrc[64], sDst[64];

  const int tid = threadIdx.x;
  const int e0 = blockIdx.x * 64;
  const int w = tid >> 6, lane = tid & 63, quad = lane >> 4, lr = lane & 15;
  if (tid < 64) {
    int e = e0 + tid;
    sSrc[tid] = (e < E) ? csr_src[e] : -1;
    sDst[tid] = (e < E) ? csr_dst[e] : -1;
  }
  __syncthreads();
  #pragma unroll
  for (int c = tid; c < 1024; c += 256) {
    int r = c >> 4;
    int kq = (c & 15) * 8;
    float pv[8];
    int sn = sSrc[r], dn = sDst[r];
    if (sn >= 0) {
      float4 u0 = *(const float4*)&uv[(size_t)dn * 256 + kq];
      float4 u1 = *(const float4*)&uv[(size_t)dn * 256 + kq + 4];
      float4 v0 = *(const float4*)&uv[(size_t)sn * 256 + 128 + kq];
      float4 v1 = *(const float4*)&uv[(size_t)sn * 256 + 128 + kq + 4];
      pv[0] = fmaxf(u0.x + v0.x, 0.f); pv[1] = fmaxf(u0.y + v0.y, 0.f);
      pv[2] = fmaxf(u0.z + v0.z, 0.f); pv[3] = fmaxf(u0.w + v0.w, 0.f);
      pv[4] = fmaxf(u1.x + v1.x, 0.f); pv[5] = fmaxf(u1.y + v1.y, 0.f);
      pv[6] = fmaxf(u1.z + v1.z, 0.f); pv[7] = fmaxf(u1.w + v1.w, 0.f);
    } else {
      #pragma unroll
      for (int i = 0; i < 8; ++i) pv[i] = 0.f;
    }
    short8 h8, l8;
    #pragma unroll
    for (int i = 0; i < 8; ++i) {
      unsigned short h = bf16_rn(pv[i]);
      h8[i] = (short)h;
      l8[i] = (short)bf16_rn(pv[i] - bf16_to_f(h));
    }
    *(short8*)&Ph[r][kq] = h8;
    *(short8*)&Pl[r][kq] = l8;
  }
  __syncthreads();
  float4v zero4 = {0.f, 0.f, 0.f, 0.f};
  float4v acc[4][2];
  #pragma unroll
  for (int mt = 0; mt < 4; ++mt)
    #pragma unroll
    for (int nt = 0; nt < 2; ++nt) acc[mt][nt] = zero4;

  #pragma unroll
  for (int k0 = 0; k0 < 128; k0 += 32) {
    short8 ah[4], alo[4], bh[2], blo[2];
    #pragma unroll
    for (int nt = 0; nt < 2; ++nt) {
      int n = w * 32 + nt * 16 + lr;
      bh[nt]  = *(const short8*)&w2Th[(size_t)n * 128 + k0 + quad * 8];
      blo[nt] = *(const short8*)&w2Tl[(size_t)n * 128 + k0 + quad * 8];
    }
    #pragma unroll
    for (int mt = 0; mt < 4; ++mt) {
      ah[mt]  = *(short8*)&Ph[mt * 16 + lr][k0 + quad * 8];
      alo[mt] = *(short8*)&Pl[mt * 16 + lr][k0 + quad * 8];
    }
    #pragma unroll
    for (int mt = 0; mt < 4; ++mt)
      #pragma unroll
      for (int nt = 0; nt < 2; ++nt) {
        acc[mt][nt] = __builtin_amdgcn_mfma_f32_16x16x32_bf16(ah[mt], bh[nt], acc[mt][nt], 0, 0, 0);
        acc[mt][nt] = __builtin_amdgcn_mfma_f32_16x16x32_bf16(alo[mt], bh[nt], acc[mt][nt], 0, 0, 0);
        acc[mt][nt] = __builtin_amdgcn_mfma_f32_16x16x32_bf16(ah[mt], blo[nt], acc[mt][nt], 0, 0, 0);
      }
  }
  __syncthreads();  // P dead; reuse as H2
  #pragma unroll
  for (int nt = 0; nt < 2; ++nt) {
    int n = w * 32 + nt * 16 + lr;
    float bv = b2[n];
    #pragma unroll
    for (int mt = 0; mt < 4; ++mt) {
      #pragma unroll
      for (int r = 0; r < 4; ++r) {
        int row = mt * 16 + quad * 4 + r;
        H2[row][n] = acc[mt][nt][r] + bv;
      }
    }
  }
  __syncthreads();
  if (tid < 128) {
    int col = tid;
    int prev = sDst[0];
    float rmax = H2[0][col];
    for (int r = 1; r < 64; ++r) {
      int d = sDst[r];
      float v = H2[r][col];
      if (d == prev) {
        rmax = fmaxf(rmax, v);
      } else {
        if (prev >= 0) atomicMaxF(&x0[(size_t)prev * 128 + col], rmax);
        prev = d;
        rmax = v;
      }
    }
    if (prev >= 0) atomicMaxF(&x0[(size_t)prev * 128 + col], rmax);
  }
}

// ---------------- GAT segment softmax + aggregation, one wave per node ----------------
__global__ __launch_bounds__(256) void k_gat_agg(const float* __restrict__ Hf,
                                                 const float* __restrict__ al,
                                                 const int* __restrict__ rs,
                                                 const int* __restrict__ csr_src,
                                                 const float* __restrict__ bias,
                                                 const float* __restrict__ res,
                                                 float* __restrict__ out,
                                                 unsigned short* __restrict__ outh,
                                                 unsigned short* __restrict__ outl, int N) {
  int wave = threadIdx.x >> 6, lane = threadIdx.x & 63;
  int i = blockIdx.x * 4 + wave;
  if (i >= N) return;
  int beg = rs[i], end = rs[i + 1];
  int deg = end - beg;
  float4 me = *(const float4*)&al[i * 4];
  float ad0 = me.z, ad1 = me.w;
  float sl0 = leaky(me.x + ad0);
  float sl1 = leaky(me.y + ad1);
  const int c = lane << 2;
  const int hsel = lane >> 5;
  float a0, a1, a2, a3;

  if (deg <= 64) {
    int s = 0;
    float l0 = -INFINITY, l1 = -INFINITY;
    bool act = lane < deg;
    if (act) {
      s = csr_src[beg + lane];
      float4 a4 = *(const float4*)&al[s * 4];
      l0 = leaky(a4.x + ad0);
      l1 = leaky(a4.y + ad1);
    }
    float m0 = fmaxf(sl0, l0), m1 = fmaxf(sl1, l1);
    #pragma unroll
    for (int o = 32; o; o >>= 1) {
      m0 = fmaxf(m0, __shfl_xor(m0, o));
      m1 = fmaxf(m1, __shfl_xor(m1, o));
    }
    float w0 = act ? __expf(l0 - m0) : 0.f;
    float w1 = act ? __expf(l1 - m1) : 0.f;
    float s0 = w0, s1 = w1;
    #pragma unroll
    for (int o = 32; o; o >>= 1) {
      s0 += __shfl_xor(s0, o);
      s1 += __shfl_xor(s1, o);
    }
    s0 += __expf(sl0 - m0);
    s1 += __expf(sl1 - m1);
    float inv0 = 1.f / (s0 + 1e-16f), inv1 = 1.f / (s1 + 1e-16f);
    float wp0 = w0 * inv0, wp1 = w1 * inv1;
    float wself = hsel ? __expf(sl1 - m1) * inv1 : __expf(sl0 - m0) * inv0;
    float4 hv = *(const float4*)&Hf[(size_t)i * 256 + c];
    a0 = wself * hv.x; a1 = wself * hv.y; a2 = wself * hv.z; a3 = wself * hv.w;
    float b0 = 0.f, b1 = 0.f, b2 = 0.f, b3 = 0.f;
    float c0 = 0.f, c1 = 0.f, c2 = 0.f, c3 = 0.f;
    float d0 = 0.f, d1 = 0.f, d2 = 0.f, d3 = 0.f;
    int j = 0;
    for (; j + 4 <= deg; j += 4) {
      int s_0 = __shfl(s, j);     float wA0 = __shfl(wp0, j);     float wB0 = __shfl(wp1, j);
      int s_1 = __shfl(s, j + 1); float wA1 = __shfl(wp0, j + 1); float wB1 = __shfl(wp1, j + 1);
      int s_2 = __shfl(s, j + 2); float wA2 = __shfl(wp0, j + 2); float wB2 = __shfl(wp1, j + 2);
      int s_3 = __shfl(s, j + 3); float wA3 = __shfl(wp0, j + 3); float wB3 = __shfl(wp1, j + 3);
      float4 h0 = *(const float4*)&Hf[(size_t)s_0 * 256 + c];
      float4 h1 = *(const float4*)&Hf[(size_t)s_1 * 256 + c];
      float4 h2 = *(const float4*)&Hf[(size_t)s_2 * 256 + c];
      float4 h3 = *(const float4*)&Hf[(size_t)s_3 * 256 + c];
      float w_0 = hsel ? wB0 : wA0;
      float w_1 = hsel ? wB1 : wA1;
      float w_2 = hsel ? wB2 : wA2;
      float w_3 = hsel ? wB3 : wA3;
      a0 += w_0 * h0.x; a1 += w_0 * h0.y; a2 += w_0 * h0.z; a3 += w_0 * h0.w;
      b0 += w_1 * h1.x; b1 += w_1 * h1.y; b2 += w_1 * h1.z; b3 += w_1 * h1.w;
      c0 += w_2 * h2.x; c1 += w_2 * h2.y; c2 += w_2 * h2.z; c3 += w_2 * h2.w;
      d0 += w_3 * h3.x; d1 += w_3 * h3.y; d2 += w_3 * h3.z; d3 += w_3 * h3.w;
    }
    for (; j < deg; ++j) {
      int sj = __shfl(s, j);
      float wA = __shfl(wp0, j), wB = __shfl(wp1, j);
      float wj = hsel ? wB : wA;
      float4 h4 = *(const float4*)&Hf[(size_t)sj * 256 + c];
      a0 += wj * h4.x; a1 += wj * h4.y; a2 += wj * h4.z; a3 += wj * h4.w;
    }
    a0 += b0 + c0 + d0; a1 += b1 + c1 + d1;
    a2 += b2 + c2 + d2; a3 += b3 + c3 + d3;
  } else {
    float m0 = sl0, m1 = sl1;
    for (int e = beg + lane; e < end; e += 64) {
      int s = csr_src[e];
      m0 = fmaxf(m0, leaky(al[s * 4 + 0] + ad0));
      m1 = fmaxf(m1, leaky(al[s * 4 + 1] + ad1));
    }
    #pragma unroll
    for (int o = 32; o; o >>= 1) {
      m0 = fmaxf(m0, __shfl_xor(m0, o));
      m1 = fmaxf(m1, __shfl_xor(m1, o));
    }
    float s0 = 0.f, s1 = 0.f;
    for (int e = beg + lane; e < end; e += 64) {
      int s = csr_src[e];
      s0 += __expf(leaky(al[s * 4 + 0] + ad0) - m0);
      s1 += __expf(leaky(al[s * 4 + 1] + ad1) - m1);
    }
    #pragma unroll
    for (int o = 32; o; o >>= 1) {
      s0 += __shfl_xor(s0, o);
      s1 += __shfl_xor(s1, o);
    }
    s0 += __expf(sl0 - m0);
    s1 += __expf(sl1 - m1);
    float inv0 = 1.f / (s0 + 1e-16f), inv1 = 1.f / (s1 + 1e-16f);
    float mh = hsel ? m1 : m0;
    float invh = hsel ? inv1 : inv0;
    float adh = hsel ? ad1 : ad0;
    float wself = __expf((hsel ? sl1 : sl0) - mh) * invh;
    float4 hv = *(const float4*)&Hf[(size_t)i * 256 + c];
    a0 = wself * hv.x; a1 = wself * hv.y; a2 = wself * hv.z; a3 = wself * hv.w;
    for (int e = beg; e < end; ++e) {
      int s = csr_src[e];
      float wgt = __expf(leaky(al[s * 4 + hsel] + adh) - mh) * invh;
      float4 h4 = *(const float4*)&Hf[(size_t)s * 256 + c];
      a0 += wgt * h4.x; a1 += wgt * h4.y; a2 += wgt * h4.z; a3 += wgt * h4.w;
    }
  }
  float4 bv = *(const float4*)&bias[c];
  float4 o4;
  o4.x = fmaxf(a0 + bv.x, 0.f);
  o4.y = fmaxf(a1 + bv.y, 0.f);
  o4.z = fmaxf(a2 + bv.z, 0.f);
  o4.w = fmaxf(a3 + bv.w, 0.f);
  if (res) {
    float4 r4 = *(const float4*)&res[(size_t)i * 256 + c];
    o4.x += r4.x; o4.y += r4.y; o4.z += r4.z; o4.w += r4.w;
  }
  size_t idx = (size_t)i * 256 + c;
  *(float4*)&out[idx] = o4;
  if (outh) {
    unsigned short hx = bf16_rn(o4.x), hy = bf16_rn(o4.y), hz = bf16_rn(o4.z), hw = bf16_rn(o4.w);
    ushort4v h4 = {hx, hy, hz, hw};
    ushort4v l4 = {bf16_rn(o4.x - bf16_to_f(hx)), bf16_rn(o4.y - bf16_to_f(hy)),
                   bf16_rn(o4.z - bf16_to_f(hz)), bf16_rn(o4.w - bf16_to_f(hw))};
    *(ushort4v*)&outh[idx] = h4;
    *(ushort4v*)&outl[idx] = l4;
  }
}

// ---------------- final projection ----------------
__global__ __launch_bounds__(256) void k_findot(const float* __restrict__ X,
                                                const float* __restrict__ fw,
                                                const float* __restrict__ fb,
                                                float* __restrict__ out, int N) {
  int wave = threadIdx.x >> 6, lane = threadIdx.x & 63;
  int i = blockIdx.x * 4 + wave;
  if (i >= N) return;
  float4 xv = *(const float4*)&X[(size_t)i * 256 + (lane << 2)];
  float4 wv = *(const float4*)&fw[lane << 2];
  float p = xv.x * wv.x + xv.y * wv.y + xv.z * wv.z + xv.w * wv.w;
  #pragma unroll
  for (int o = 32; o; o >>= 1) p += __shfl_xor(p, o);
  if (lane == 0) out[i] = p + fb[0];
}

// ---------------------------------------------------------------------------
extern "C" void kernel_launch(void* const* d_in, const int* in_sizes, int n_in,
                              void* d_out, int out_size, void* d_ws, size_t ws_size,
                              hipStream_t stream) {
  const float* x      = (const float*)d_in[0];
  const int*   ei     = (const int*)d_in[1];
  const float* ec_w1  = (const float*)d_in[3];
  const float* ec_b1  = (const float*)d_in[4];
  const float* ec_w2  = (const float*)d_in[5];
  const float* ec_b2  = (const float*)d_in[6];
  const float* reg_w  = (const float*)d_in[7];
  const float* reg_b  = (const float*)d_in[8];
  const float* fin_w  = (const float*)d_in[9];
  const float* fin_b  = (const float*)d_in[10];
  const float* g1_w   = (const float*)d_in[11];
  const float* g1_as  = (const float*)d_in[12];
  const float* g1_ad  = (const float*)d_in[13];
  const float* g1_b   = (const float*)d_in[14];
  const float* g2_w   = (const float*)d_in[15];
  const float* g2_as  = (const float*)d_in[16];
  const float* g2_ad  = (const float*)d_in[17];
  const float* g2_b   = (const float*)d_in[18];
  const float* g3_w   = (const float*)d_in[19];
  const float* g3_as  = (const float*)d_in[20];
  const float* g3_ad  = (const float*)d_in[21];
  const float* g3_b   = (const float*)d_in[22];
  const float* g4_w   = (const float*)d_in[23];
  const float* g4_as  = (const float*)d_in[24];
  const float* g4_ad  = (const float*)d_in[25];
  const float* g4_b   = (const float*)d_in[26];

  const int N = in_sizes[0] / 128;
  const int E = in_sizes[1] / 2;

  char* base = (char*)d_ws;
  size_t off = 0;
  auto alloc = [&](size_t bytes) -> char* {
    char* p = base + off;
    off += (bytes + 255) & ~(size_t)255;
    return p;
  };
  const size_t szN4 = ((size_t)N * 4 + 255) & ~(size_t)255;
  int*   deg      = (int*)alloc((size_t)N * 4);
  int*   cnt      = (int*)alloc((size_t)N * 4);
  int*   rs       = (int*)alloc((size_t)(N + 1) * 4);
  int*   csr_src  = (int*)alloc((size_t)E * 4);
  int*   csr_dst  = (int*)alloc((size_t)E * 4);
  float* bias_cat = (float*)alloc(256 * 4);
  unsigned short* bcatTh = (unsigned short*)alloc(256 * 128 * 2);
  unsigned short* bcatTl = (unsigned short*)alloc(256 * 128 * 2);
  unsigned short* w2Th   = (unsigned short*)alloc(128 * 128 * 2);
  unsigned short* w2Tl   = (unsigned short*)alloc(128 * 128 * 2);
  unsigned short* g1Th   = (unsigned short*)alloc(256 * 128 * 2);
  unsigned short* g1Tl   = (unsigned short*)alloc(256 * 128 * 2);
  unsigned short* g2Th   = (unsigned short*)alloc(256 * 256 * 2);
  unsigned short* g2Tl   = (unsigned short*)alloc(256 * 256 * 2);
  unsigned short* g3Th   = (unsigned short*)alloc(256 * 256 * 2);
  unsigned short* g3Tl   = (unsigned short*)alloc(256 * 256 * 2);
  unsigned short* g4Th   = (unsigned short*)alloc(256 * 256 * 2);
  unsigned short* g4Tl   = (unsigned short*)alloc(256 * 256 * 2);
  unsigned short* regTh  = (unsigned short*)alloc(256 * 256 * 2);
  unsigned short* regTl  = (unsigned short*)alloc(256 * 256 * 2);
  float* uv = (float*)alloc((size_t)N * 256 * 4);
  float* x0 = (float*)alloc((size_t)N * 128 * 4);
  float* X1 = (float*)alloc((size_t)N * 256 * 4);
  float* X2 = (float*)alloc((size_t)N * 256 * 4);
  float* al = (float*)alloc((size_t)N * 4 * 4);
  unsigned short* s1h = (unsigned short*)alloc((size_t)N * 256 * 2);
  unsigned short* s1l = (unsigned short*)alloc((size_t)N * 256 * 2);
  unsigned short* s2h = (unsigned short*)alloc((size_t)N * 256 * 2);
  unsigned short* s2l = (unsigned short*)alloc((size_t)N * 256 * 2);
  (void)ws_size; (void)n_in; (void)out_size;

  const int nodeWaveBlocks = (N + 3) / 4;
  const dim3 gemmGrid((N + 127) / 128, 2);
  const int splitBlocks128 = (N * 128 / 4 + 255) / 256;

  // --- weight prep ---
  SplitJobs jobs;
  jobs.j[0] = {ec_w2, nullptr, w2Th, w2Tl, nullptr, 128, 128, 7, 0};
  jobs.j[1] = {g1_w,  nullptr, g1Th, g1Tl, nullptr, 128, 256, 7, 0};
  jobs.j[2] = {g2_w,  nullptr, g2Th, g2Tl, nullptr, 256, 256, 8, 0};
  jobs.j[3] = {g3_w,  nullptr, g3Th, g3Tl, nullptr, 256, 256, 8, 0};
  jobs.j[4] = {g4_w,  nullptr, g4Th, g4Tl, nullptr, 256, 256, 8, 0};
  jobs.j[5] = {reg_w, nullptr, regTh, regTl, nullptr, 256, 256, 8, 0};
  jobs.j[6] = {ec_w1, ec_b1, bcatTh, bcatTl, bias_cat, 128, 256, 7, 1};
  k_prep_all<<<dim3(256, 7), 256, 0, stream>>>(jobs);

  // --- CSR build ---
  hipMemsetAsync(deg, 0, 2 * szN4, stream);
  k_hist<<<(E + 255) / 256, 256, 0, stream>>>(ei, deg, E);
  k_scan<<<1, 1024, 0, stream>>>(deg, rs, N);
  k_scatter<<<(E + 255) / 256, 256, 0, stream>>>(ei, rs, cnt, csr_src, csr_dst, E);

  // --- EdgeConv ---
  k_split_act<<<splitBlocks128, 256, 0, stream>>>(x, s1h, s1l, N * 128, 0);
  k_gemm_mfma<<<gemmGrid, 256, 0, stream>>>(s1h, s1l, bcatTh, bcatTl, bias_cat, uv, N, 128,
                                            nullptr, nullptr, nullptr, nullptr, nullptr);
  k_fill_f32<<<(N * 128 + 255) / 256, 256, 0, stream>>>(x0, -INFINITY, N * 128);
  k_edgeconv2<<<(E + 63) / 64, 256, 0, stream>>>(uv, csr_src, csr_dst, w2Th, w2Tl, ec_b2, x0, E);
  k_split_act<<<splitBlocks128, 256, 0, stream>>>(x0, s1h, s1l, N * 128, 1);

  // --- GAT1: X1 = relu(gat(x0)) ---
  k_gemm_mfma<<<gemmGrid, 256, 0, stream>>>(s1h, s1l, g1Th, g1Tl, nullptr, uv, N, 128,
                                            nullptr, nullptr, g1_as, g1_ad, al);
  k_gat_agg<<<nodeWaveBlocks, 256, 0, stream>>>(uv, al, rs, csr_src, g1_b, nullptr, X1,
                                                s1h, s1l, N);

  // --- GAT2: X2 = relu(gat(X1)) + X1 ---
  k_gemm_mfma<<<gemmGrid, 256, 0, stream>>>(s1h, s1l, g2Th, g2Tl, nullptr, uv, N, 256,
                                            nullptr, nullptr, g2_as, g2_ad, al);
  k_gat_agg<<<nodeWaveBlocks, 256, 0, stream>>>(uv, al, rs, csr_src, g2_b, X1, X2,
                                                s2h, s2l, N);

  // --- reg: X1 = X2 @ reg_w + reg_b (fp32 + split) ---
  k_gemm_mfma<<<gemmGrid, 256, 0, stream>>>(s2h, s2l, regTh, regTl, reg_b, X1, N, 256,
                                            s1h, s1l, nullptr, nullptr, nullptr);

  // --- GAT3: X2 = relu(gat(X1)) + X1 ---
  k_gemm_mfma<<<gemmGrid, 256, 0, stream>>>(s1h, s1l, g3Th, g3Tl, nullptr, uv, N, 256,
                                            nullptr, nullptr, g3_as, g3_ad, al);
  k_gat_agg<<<nodeWaveBlocks, 256, 0, stream>>>(uv, al, rs, csr_src, g3_b, X1, X2,
                                                s2h, s2l, N);

  // --- GAT4: X1 = relu(gat(X2)) ---
  k_gemm_mfma<<<gemmGrid, 256, 0, stream>>>(s2h, s2l, g4Th, g4Tl, nullptr, uv, N, 256,
                                            nullptr, nullptr, g4_as, g4_ad, al);
  k_gat_agg<<<nodeWaveBlocks, 256, 0, stream>>>(uv, al, rs, csr_src, g4_b, nullptr, X1,
                                                nullptr, nullptr, N);

  // --- final linear ---
  k_findot<<<nodeWaveBlocks, 256, 0, stream>>>(X1, fin_w, fin_b, (float*)d_out, N);
}

// Round 7
// 618.831 us; speedup vs baseline: 1.1244x; 1.0388x over previous
//
#include <hip/hip_runtime.h>
#include <math.h>

// ---------------------------------------------------------------------------
// SymmetricalResidualGAT: EdgeConv(max) + GAT x4 (H=2, C=128) + linears.
// N=20000, E=320000. Round 7: round 6 structure with the head-weight shuffle
// bug fixed (shuffle wp0/wp1 separately, select by hsel AFTER the shuffle).
// ---------------------------------------------------------------------------

#define NEG_SLOPE 0.2f

typedef short short8 __attribute__((ext_vector_type(8)));
typedef float float4v __attribute__((ext_vector_type(4)));
typedef unsigned short ushort4v __attribute__((ext_vector_type(4)));

#define AS1 __attribute__((address_space(1)))
#define AS3 __attribute__((address_space(3)))

__device__ __forceinline__ void cp16(const void* g, void* l) {
  // async global->LDS, 16B/lane; LDS dest = wave-uniform base + lane*16
  __builtin_amdgcn_global_load_lds((const AS1 unsigned int*)g, (AS3 unsigned int*)l, 16, 0, 0);
}

__device__ __forceinline__ float leaky(float x) { return x > 0.f ? x : NEG_SLOPE * x; }

__device__ __forceinline__ void atomicMaxF(float* addr, float v) {
  if (v >= 0.f) atomicMax((int*)addr, __float_as_int(v));
  else          atomicMin((unsigned int*)addr, __float_as_uint(v));
}

__device__ __forceinline__ unsigned short bf16_rn(float f) {
  unsigned u = __float_as_uint(f);
  unsigned r = (u + 0x7FFFu + ((u >> 16) & 1u)) >> 16;
  return (unsigned short)r;
}
__device__ __forceinline__ float bf16_to_f(unsigned short h) {
  return __uint_as_float(((unsigned)h) << 16);
}

// ---------------- small kernels ----------------
__global__ __launch_bounds__(256) void k_fill_f32(float* p, float v, int n) {
  int i = blockIdx.x * 256 + threadIdx.x;
  if (i < n) p[i] = v;
}

__global__ __launch_bounds__(256) void k_split_act(const float* __restrict__ src,
                                                   unsigned short* __restrict__ h,
                                                   unsigned short* __restrict__ l,
                                                   int n, int fixinf) {
  int i4 = (blockIdx.x * 256 + threadIdx.x) * 4;
  if (i4 >= n) return;
  float4 v = *(const float4*)&src[i4];
  if (fixinf) {
    if (v.x == -INFINITY) v.x = 0.f;
    if (v.y == -INFINITY) v.y = 0.f;
    if (v.z == -INFINITY) v.z = 0.f;
    if (v.w == -INFINITY) v.w = 0.f;
  }
  unsigned short hx = bf16_rn(v.x), hy = bf16_rn(v.y), hz = bf16_rn(v.z), hw = bf16_rn(v.w);
  ushort4v h4 = {hx, hy, hz, hw};
  ushort4v l4 = {bf16_rn(v.x - bf16_to_f(hx)), bf16_rn(v.y - bf16_to_f(hy)),
                 bf16_rn(v.z - bf16_to_f(hz)), bf16_rn(v.w - bf16_to_f(hw))};
  *(ushort4v*)&h[i4] = h4;
  *(ushort4v*)&l[i4] = l4;
}

__global__ __launch_bounds__(256) void k_hist(const int* __restrict__ ei, int* __restrict__ deg,
                                              int E) {
  int e = blockIdx.x * 256 + threadIdx.x;
  if (e < E) atomicAdd(&deg[ei[E + e]], 1);
}

__global__ __launch_bounds__(1024) void k_scan(const int* __restrict__ deg, int* __restrict__ rs,
                                               int n) {
  __shared__ int wsum[16];
  __shared__ int carry;
  int tid = threadIdx.x, lane = tid & 63, wv = tid >> 6;
  if (tid == 0) carry = 0;
  __syncthreads();
  for (int base = 0; base < n; base += 1024) {
    int i = base + tid;
    int v = (i < n) ? deg[i] : 0;
    int s = v;
    #pragma unroll
    for (int o = 1; o < 64; o <<= 1) {
      int t = __shfl(s, lane - o);
      if (lane >= o) s += t;
    }
    if (lane == 63) wsum[wv] = s;
    __syncthreads();
    if (wv == 0) {
      int x = (lane < 16) ? wsum[lane] : 0;
      #pragma unroll
      for (int o = 1; o < 16; o <<= 1) {
        int t = __shfl(x, lane - o);
        if (lane >= o) x += t;
      }
      if (lane < 16) wsum[lane] = x;
    }
    __syncthreads();
    int woff = carry + (wv ? wsum[wv - 1] : 0);
    if (i < n) rs[i] = woff + s - v;
    __syncthreads();
    if (tid == 0) carry += wsum[15];
    __syncthreads();
  }
  if (tid == 0) rs[n] = carry;
}

__global__ __launch_bounds__(256) void k_scatter(const int* __restrict__ ei,
                                                 const int* __restrict__ rs,
                                                 int* __restrict__ cnt,
                                                 int* __restrict__ csr_src,
                                                 int* __restrict__ csr_dst, int E) {
  int e = blockIdx.x * 256 + threadIdx.x;
  if (e < E) {
    int d = ei[E + e];
    int p = atomicAdd(&cnt[d], 1);
    int slot = rs[d] + p;
    csr_src[slot] = ei[e];
    csr_dst[slot] = d;
  }
}

// ---------------- one-shot weight prep: transpose + hi/lo bf16 split ----------------
struct SplitJob {
  const float* W;
  const float* aux;
  unsigned short* Th;
  unsigned short* Tl;
  float* bias_out;
  int K, N, kshift, type;
};
struct SplitJobs { SplitJob j[7]; };

__global__ __launch_bounds__(256) void k_prep_all(SplitJobs jobs) {
  SplitJob jb = jobs.j[blockIdx.y];
  int idx = blockIdx.x * 256 + threadIdx.x;
  if (idx >= jb.K * jb.N) return;
  float v;
  if (jb.type == 0) {
    int n = idx >> jb.kshift;
    int k = idx & (jb.K - 1);
    v = jb.W[k * jb.N + n];
  } else {
    int n = idx >> 7;
    int k = idx & 127;
    if (n < 128) v = jb.W[k * 128 + n] - jb.W[(k + 128) * 128 + n];
    else         v = jb.W[(k + 128) * 128 + (n - 128)];
    if (idx < 256) jb.bias_out[idx] = (idx < 128) ? jb.aux[idx] : 0.f;
  }
  unsigned short h = bf16_rn(v);
  jb.Th[idx] = h;
  jb.Tl[idx] = bf16_rn(v - bf16_to_f(h));
}

// ---------------- MFMA split-bf16 GEMM, 64x128 tile, LDS fragment-order ----------------
__global__ __launch_bounds__(256) void k_gemm_mfma(const unsigned short* __restrict__ Ah,
                                                   const unsigned short* __restrict__ Al,
                                                   const unsigned short* __restrict__ BTh,
                                                   const unsigned short* __restrict__ BTl,
                                                   const float* __restrict__ bias,
                                                   float* __restrict__ C, int M, int K,
                                                   unsigned short* __restrict__ Ch,
                                                   unsigned short* __restrict__ Cl,
                                                   const float* __restrict__ a_s,
                                                   const float* __restrict__ a_d,
                                                   float* __restrict__ al_out) {
  __shared__ __align__(16) char sm[24576];   // AhS(4K) AlS(4K) BhS(8K) BlS(8K)
  __shared__ float alS[64][2];
  char* AhS = sm;
  char* AlS = sm + 4096;
  char* BhS = sm + 8192;
  char* BlS = sm + 16384;

  const int tid = threadIdx.x;
  const int bm = blockIdx.x * 64;
  const int bn = blockIdx.y * 128;
  const int w = tid >> 6, lane = tid & 63, quad = lane >> 4, lr = lane & 15;
  const int kq8 = quad * 8;

  float4v zero4 = {0.f, 0.f, 0.f, 0.f};
  float4v acc[4][2];
  #pragma unroll
  for (int mt = 0; mt < 4; ++mt)
    #pragma unroll
    for (int nt = 0; nt < 2; ++nt) acc[mt][nt] = zero4;

  // staging: wave w stages A tile w (hi+lo) and B tiles 2w, 2w+1 (hi+lo)
  int ar = bm + w * 16 + lr; if (ar >= M) ar = M - 1;
  const size_t aoff  = (size_t)ar * K + kq8;
  const size_t boff0 = (size_t)(bn + (2 * w) * 16 + lr) * K + kq8;
  const size_t boff1 = (size_t)(bn + (2 * w + 1) * 16 + lr) * K + kq8;
  char* lA   = AhS + w * 1024;
  char* lAl  = AlS + w * 1024;
  char* lB0  = BhS + (2 * w) * 1024;
  char* lB1  = BhS + (2 * w + 1) * 1024;
  char* lBl0 = BlS + (2 * w) * 1024;
  char* lBl1 = BlS + (2 * w + 1) * 1024;

  for (int k0 = 0; k0 < K; k0 += 32) {
    __syncthreads();
    cp16(Ah + aoff + k0, lA);
    cp16(Al + aoff + k0, lAl);
    cp16(BTh + boff0 + k0, lB0);
    cp16(BTh + boff1 + k0, lB1);
    cp16(BTl + boff0 + k0, lBl0);
    cp16(BTl + boff1 + k0, lBl1);
    __syncthreads();
    short8 ah[4], alo[4], bh[2], blo[2];
    #pragma unroll
    for (int mt = 0; mt < 4; ++mt) {
      ah[mt]  = *(const short8*)(AhS + mt * 1024 + lane * 16);
      alo[mt] = *(const short8*)(AlS + mt * 1024 + lane * 16);
    }
    #pragma unroll
    for (int nt = 0; nt < 2; ++nt) {
      bh[nt]  = *(const short8*)(BhS + (2 * w + nt) * 1024 + lane * 16);
      blo[nt] = *(const short8*)(BlS + (2 * w + nt) * 1024 + lane * 16);
    }
    #pragma unroll
    for (int mt = 0; mt < 4; ++mt)
      #pragma unroll
      for (int nt = 0; nt < 2; ++nt) {
        acc[mt][nt] = __builtin_amdgcn_mfma_f32_16x16x32_bf16(ah[mt], bh[nt], acc[mt][nt], 0, 0, 0);
        acc[mt][nt] = __builtin_amdgcn_mfma_f32_16x16x32_bf16(alo[mt], bh[nt], acc[mt][nt], 0, 0, 0);
        acc[mt][nt] = __builtin_amdgcn_mfma_f32_16x16x32_bf16(ah[mt], blo[nt], acc[mt][nt], 0, 0, 0);
      }
  }
  // ---- C store (layout col=lane&15, row=quad*4+reg) ----
  #pragma unroll
  for (int nt = 0; nt < 2; ++nt) {
    int n = bn + w * 32 + nt * 16 + lr;
    float bv = bias ? bias[n] : 0.f;
    #pragma unroll
    for (int mt = 0; mt < 4; ++mt) {
      #pragma unroll
      for (int r = 0; r < 4; ++r) {
        int m = bm + mt * 16 + quad * 4 + r;
        if (m < M) {
          float v = acc[mt][nt][r] + bv;
          size_t idx = (size_t)m * 256 + n;
          C[idx] = v;
          if (Ch) {
            unsigned short h = bf16_rn(v);
            Ch[idx] = h;
            Cl[idx] = bf16_rn(v - bf16_to_f(h));
          }
        }
      }
    }
  }
  // ---- fused attention logits (block y == head) ----
  if (a_s) {
    if (tid < 128) ((float*)alS)[tid] = 0.f;
    __syncthreads();
    float asv[2], adv[2];
    #pragma unroll
    for (int nt = 0; nt < 2; ++nt) {
      int n = bn + w * 32 + nt * 16 + lr;
      asv[nt] = a_s[n];
      adv[nt] = a_d[n];
    }
    #pragma unroll
    for (int mt = 0; mt < 4; ++mt) {
      #pragma unroll
      for (int r = 0; r < 4; ++r) {
        float ps = acc[mt][0][r] * asv[0] + acc[mt][1][r] * asv[1];
        float pd = acc[mt][0][r] * adv[0] + acc[mt][1][r] * adv[1];
        #pragma unroll
        for (int o = 8; o; o >>= 1) {
          ps += __shfl_xor(ps, o);
          pd += __shfl_xor(pd, o);
        }
        if (lr == 0) {
          int row = mt * 16 + quad * 4 + r;
          atomicAdd(&alS[row][0], ps);
          atomicAdd(&alS[row][1], pd);
        }
      }
    }
    __syncthreads();
    int head = bn >> 7;
    if (tid < 64) {
      int m = bm + tid;
      if (m < M) {
        al_out[m * 4 + head]     = alS[tid][0];
        al_out[m * 4 + 2 + head] = alS[tid][1];
      }
    }
  }
}

// ---------------- EdgeConv: P=relu(u[dst]+v[src]); H2=P@W2+b2; segment-max ----------------
__global__ __launch_bounds__(256, 4) void k_edgeconv2(const float* __restrict__ uv,
                                                      const int* __restrict__ csr_src,
                                                      const int* __restrict__ csr_dst,
                                                      const unsigned short* __restrict__ w2Th,
                                                      const unsigned short* __restrict__ w2Tl,
                                                      const float* __restrict__ b2,
                                                      float* __restrict__ x0, int E) {
  __shared__ __align__(16) char smem[34816];
  unsigned short (*Ph)[136] = (unsigned short(*)[136])smem;            // 17408 B
  unsigned short (*Pl)[136] = (unsigned short(*)[136])(smem + 17408);  // 17408 B
  float (*H2)[132] = (float(*)[132])smem;                              // alias, 33792 B
  __shared__ int sSrc[64], sDst[64];

  const int tid = threadIdx.x;
  const int e0 = blockIdx.x * 64;
  const int w = tid >> 6, lane = tid & 63, quad = lane >> 4, lr = lane & 15;
  if (tid < 64) {
    int e = e0 + tid;
    sSrc[tid] = (e < E) ? csr_src[e] : -1;
    sDst[tid] = (e < E) ? csr_dst[e] : -1;
  }
  __syncthreads();
  #pragma unroll
  for (int c = tid; c < 1024; c += 256) {
    int r = c >> 4;
    int kq = (c & 15) * 8;
    float pv[8];
    int sn = sSrc[r], dn = sDst[r];
    if (sn >= 0) {
      float4 u0 = *(const float4*)&uv[(size_t)dn * 256 + kq];
      float4 u1 = *(const float4*)&uv[(size_t)dn * 256 + kq + 4];
      float4 v0 = *(const float4*)&uv[(size_t)sn * 256 + 128 + kq];
      float4 v1 = *(const float4*)&uv[(size_t)sn * 256 + 128 + kq + 4];
      pv[0] = fmaxf(u0.x + v0.x, 0.f); pv[1] = fmaxf(u0.y + v0.y, 0.f);
      pv[2] = fmaxf(u0.z + v0.z, 0.f); pv[3] = fmaxf(u0.w + v0.w, 0.f);
      pv[4] = fmaxf(u1.x + v1.x, 0.f); pv[5] = fmaxf(u1.y + v1.y, 0.f);
      pv[6] = fmaxf(u1.z + v1.z, 0.f); pv[7] = fmaxf(u1.w + v1.w, 0.f);
    } else {
      #pragma unroll
      for (int i = 0; i < 8; ++i) pv[i] = 0.f;
    }
    short8 h8, l8;
    #pragma unroll
    for (int i = 0; i < 8; ++i) {
      unsigned short h = bf16_rn(pv[i]);
      h8[i] = (short)h;
      l8[i] = (short)bf16_rn(pv[i] - bf16_to_f(h));
    }
    *(short8*)&Ph[r][kq] = h8;
    *(short8*)&Pl[r][kq] = l8;
  }
  __syncthreads();
  float4v zero4 = {0.f, 0.f, 0.f, 0.f};
  float4v acc[4][2];
  #pragma unroll
  for (int mt = 0; mt < 4; ++mt)
    #pragma unroll
    for (int nt = 0; nt < 2; ++nt) acc[mt][nt] = zero4;

  #pragma unroll
  for (int k0 = 0; k0 < 128; k0 += 32) {
    short8 ah[4], alo[4], bh[2], blo[2];
    #pragma unroll
    for (int nt = 0; nt < 2; ++nt) {
      int n = w * 32 + nt * 16 + lr;
      bh[nt]  = *(const short8*)&w2Th[(size_t)n * 128 + k0 + quad * 8];
      blo[nt] = *(const short8*)&w2Tl[(size_t)n * 128 + k0 + quad * 8];
    }
    #pragma unroll
    for (int mt = 0; mt < 4; ++mt) {
      ah[mt]  = *(short8*)&Ph[mt * 16 + lr][k0 + quad * 8];
      alo[mt] = *(short8*)&Pl[mt * 16 + lr][k0 + quad * 8];
    }
    #pragma unroll
    for (int mt = 0; mt < 4; ++mt)
      #pragma unroll
      for (int nt = 0; nt < 2; ++nt) {
        acc[mt][nt] = __builtin_amdgcn_mfma_f32_16x16x32_bf16(ah[mt], bh[nt], acc[mt][nt], 0, 0, 0);
        acc[mt][nt] = __builtin_amdgcn_mfma_f32_16x16x32_bf16(alo[mt], bh[nt], acc[mt][nt], 0, 0, 0);
        acc[mt][nt] = __builtin_amdgcn_mfma_f32_16x16x32_bf16(ah[mt], blo[nt], acc[mt][nt], 0, 0, 0);
      }
  }
  __syncthreads();  // P dead; reuse as H2
  #pragma unroll
  for (int nt = 0; nt < 2; ++nt) {
    int n = w * 32 + nt * 16 + lr;
    float bv = b2[n];
    #pragma unroll
    for (int mt = 0; mt < 4; ++mt) {
      #pragma unroll
      for (int r = 0; r < 4; ++r) {
        int row = mt * 16 + quad * 4 + r;
        H2[row][n] = acc[mt][nt][r] + bv;
      }
    }
  }
  __syncthreads();
  if (tid < 128) {
    int col = tid;
    int prev = sDst[0];
    float rmax = H2[0][col];
    for (int r = 1; r < 64; ++r) {
      int d = sDst[r];
      float v = H2[r][col];
      if (d == prev) {
        rmax = fmaxf(rmax, v);
      } else {
        if (prev >= 0) atomicMaxF(&x0[(size_t)prev * 128 + col], rmax);
        prev = d;
        rmax = v;
      }
    }
    if (prev >= 0) atomicMaxF(&x0[(size_t)prev * 128 + col], rmax);
  }
}

// ---------------- GAT segment softmax + aggregation, one wave per node ----------------
// If finw != null: instead of storing features, compute out[i] = dot(feat, finw) + finb.
__global__ __launch_bounds__(256) void k_gat_agg(const float* __restrict__ Hf,
                                                 const float* __restrict__ al,
                                                 const int* __restrict__ rs,
                                                 const int* __restrict__ csr_src,
                                                 const float* __restrict__ bias,
                                                 const float* __restrict__ res,
                                                 float* __restrict__ out,
                                                 unsigned short* __restrict__ outh,
                                                 unsigned short* __restrict__ outl,
                                                 const float* __restrict__ finw,
                                                 const float* __restrict__ finb, int N) {
  int wave = threadIdx.x >> 6, lane = threadIdx.x & 63;
  int i = blockIdx.x * 4 + wave;
  if (i >= N) return;
  int beg = rs[i], end = rs[i + 1];
  int deg = end - beg;
  float4 me = *(const float4*)&al[i * 4];
  float ad0 = me.z, ad1 = me.w;
  float sl0 = leaky(me.x + ad0);
  float sl1 = leaky(me.y + ad1);
  const int c = lane << 2;
  const int hsel = lane >> 5;
  float a0, a1, a2, a3;

  if (deg <= 64) {
    int s = 0;
    float l0 = -INFINITY, l1 = -INFINITY;
    bool act = lane < deg;
    if (act) {
      s = csr_src[beg + lane];
      float4 a4 = *(const float4*)&al[s * 4];
      l0 = leaky(a4.x + ad0);
      l1 = leaky(a4.y + ad1);
    }
    float m0 = fmaxf(sl0, l0), m1 = fmaxf(sl1, l1);
    #pragma unroll
    for (int o = 32; o; o >>= 1) {
      m0 = fmaxf(m0, __shfl_xor(m0, o));
      m1 = fmaxf(m1, __shfl_xor(m1, o));
    }
    float w0 = act ? __expf(l0 - m0) : 0.f;
    float w1 = act ? __expf(l1 - m1) : 0.f;
    float s0 = w0, s1 = w1;
    #pragma unroll
    for (int o = 32; o; o >>= 1) {
      s0 += __shfl_xor(s0, o);
      s1 += __shfl_xor(s1, o);
    }
    s0 += __expf(sl0 - m0);
    s1 += __expf(sl1 - m1);
    float inv0 = 1.f / (s0 + 1e-16f), inv1 = 1.f / (s1 + 1e-16f);
    float wp0 = w0 * inv0, wp1 = w1 * inv1;
    float wself = hsel ? __expf(sl1 - m1) * inv1 : __expf(sl0 - m0) * inv0;
    float4 hv = *(const float4*)&Hf[(size_t)i * 256 + c];
    a0 = wself * hv.x; a1 = wself * hv.y; a2 = wself * hv.z; a3 = wself * hv.w;
    float b0 = 0.f, b1 = 0.f, b2 = 0.f, b3 = 0.f;
    float c0 = 0.f, c1 = 0.f, c2 = 0.f, c3 = 0.f;
    float d0 = 0.f, d1 = 0.f, d2 = 0.f, d3 = 0.f;
    int j = 0;
    for (; j + 8 <= deg; j += 8) {
      int   sjj[8];
      float wjj[8];
      #pragma unroll
      for (int q = 0; q < 8; ++q) {
        sjj[q] = __shfl(s, j + q);
        // NOTE: must shuffle BOTH head weights and select with the RECEIVER's
        // hsel — selecting before the shuffle uses the source lane's head (bug
        // in round 6: mixed head-0/head-1 softmax weights, absmax 4.7e-2).
        float wA = __shfl(wp0, j + q);
        float wB = __shfl(wp1, j + q);
        wjj[q] = hsel ? wB : wA;
      }
      float4 h0 = *(const float4*)&Hf[(size_t)sjj[0] * 256 + c];
      float4 h1 = *(const float4*)&Hf[(size_t)sjj[1] * 256 + c];
      float4 h2 = *(const float4*)&Hf[(size_t)sjj[2] * 256 + c];
      float4 h3 = *(const float4*)&Hf[(size_t)sjj[3] * 256 + c];
      float4 h4 = *(const float4*)&Hf[(size_t)sjj[4] * 256 + c];
      float4 h5 = *(const float4*)&Hf[(size_t)sjj[5] * 256 + c];
      float4 h6 = *(const float4*)&Hf[(size_t)sjj[6] * 256 + c];
      float4 h7 = *(const float4*)&Hf[(size_t)sjj[7] * 256 + c];
      a0 += wjj[0] * h0.x; a1 += wjj[0] * h0.y; a2 += wjj[0] * h0.z; a3 += wjj[0] * h0.w;
      b0 += wjj[1] * h1.x; b1 += wjj[1] * h1.y; b2 += wjj[1] * h1.z; b3 += wjj[1] * h1.w;
      c0 += wjj[2] * h2.x; c1 += wjj[2] * h2.y; c2 += wjj[2] * h2.z; c3 += wjj[2] * h2.w;
      d0 += wjj[3] * h3.x; d1 += wjj[3] * h3.y; d2 += wjj[3] * h3.z; d3 += wjj[3] * h3.w;
      a0 += wjj[4] * h4.x; a1 += wjj[4] * h4.y; a2 += wjj[4] * h4.z; a3 += wjj[4] * h4.w;
      b0 += wjj[5] * h5.x; b1 += wjj[5] * h5.y; b2 += wjj[5] * h5.z; b3 += wjj[5] * h5.w;
      c0 += wjj[6] * h6.x; c1 += wjj[6] * h6.y; c2 += wjj[6] * h6.z; c3 += wjj[6] * h6.w;
      d0 += wjj[7] * h7.x; d1 += wjj[7] * h7.y; d2 += wjj[7] * h7.z; d3 += wjj[7] * h7.w;
    }
    for (; j < deg; ++j) {
      int sj = __shfl(s, j);
      float wA = __shfl(wp0, j);
      float wB = __shfl(wp1, j);
      float wj = hsel ? wB : wA;
      float4 h4 = *(const float4*)&Hf[(size_t)sj * 256 + c];
      a0 += wj * h4.x; a1 += wj * h4.y; a2 += wj * h4.z; a3 += wj * h4.w;
    }
    a0 += b0 + c0 + d0; a1 += b1 + c1 + d1;
    a2 += b2 + c2 + d2; a3 += b3 + c3 + d3;
  } else {
    float m0 = sl0, m1 = sl1;
    for (int e = beg + lane; e < end; e += 64) {
      int s = csr_src[e];
      m0 = fmaxf(m0, leaky(al[s * 4 + 0] + ad0));
      m1 = fmaxf(m1, leaky(al[s * 4 + 1] + ad1));
    }
    #pragma unroll
    for (int o = 32; o; o >>= 1) {
      m0 = fmaxf(m0, __shfl_xor(m0, o));
      m1 = fmaxf(m1, __shfl_xor(m1, o));
    }
    float s0 = 0.f, s1 = 0.f;
    for (int e = beg + lane; e < end; e += 64) {
      int s = csr_src[e];
      s0 += __expf(leaky(al[s * 4 + 0] + ad0) - m0);
      s1 += __expf(leaky(al[s * 4 + 1] + ad1) - m1);
    }
    #pragma unroll
    for (int o = 32; o; o >>= 1) {
      s0 += __shfl_xor(s0, o);
      s1 += __shfl_xor(s1, o);
    }
    s0 += __expf(sl0 - m0);
    s1 += __expf(sl1 - m1);
    float inv0 = 1.f / (s0 + 1e-16f), inv1 = 1.f / (s1 + 1e-16f);
    float mh = hsel ? m1 : m0;
    float invh = hsel ? inv1 : inv0;
    float adh = hsel ? ad1 : ad0;
    float wself = __expf((hsel ? sl1 : sl0) - mh) * invh;
    float4 hv = *(const float4*)&Hf[(size_t)i * 256 + c];
    a0 = wself * hv.x; a1 = wself * hv.y; a2 = wself * hv.z; a3 = wself * hv.w;
    for (int e = beg; e < end; ++e) {
      int s = csr_src[e];
      float wgt = __expf(leaky(al[s * 4 + hsel] + adh) - mh) * invh;
      float4 h4 = *(const float4*)&Hf[(size_t)s * 256 + c];
      a0 += wgt * h4.x; a1 += wgt * h4.y; a2 += wgt * h4.z; a3 += wgt * h4.w;
    }
  }
  float4 bv = *(const float4*)&bias[c];
  float4 o4;
  o4.x = fmaxf(a0 + bv.x, 0.f);
  o4.y = fmaxf(a1 + bv.y, 0.f);
  o4.z = fmaxf(a2 + bv.z, 0.f);
  o4.w = fmaxf(a3 + bv.w, 0.f);
  if (res) {
    float4 r4 = *(const float4*)&res[(size_t)i * 256 + c];
    o4.x += r4.x; o4.y += r4.y; o4.z += r4.z; o4.w += r4.w;
  }
  if (finw) {
    // fused final projection: out[i] = dot(feat, finw) + finb
    float4 wv = *(const float4*)&finw[c];
    float p = o4.x * wv.x + o4.y * wv.y + o4.z * wv.z + o4.w * wv.w;
    #pragma unroll
    for (int o = 32; o; o >>= 1) p += __shfl_xor(p, o);
    if (lane == 0) out[i] = p + finb[0];
    return;
  }
  size_t idx = (size_t)i * 256 + c;
  *(float4*)&out[idx] = o4;
  if (outh) {
    unsigned short hx = bf16_rn(o4.x), hy = bf16_rn(o4.y), hz = bf16_rn(o4.z), hw = bf16_rn(o4.w);
    ushort4v h4 = {hx, hy, hz, hw};
    ushort4v l4 = {bf16_rn(o4.x - bf16_to_f(hx)), bf16_rn(o4.y - bf16_to_f(hy)),
                   bf16_rn(o4.z - bf16_to_f(hz)), bf16_rn(o4.w - bf16_to_f(hw))};
    *(ushort4v*)&outh[idx] = h4;
    *(ushort4v*)&outl[idx] = l4;
  }
}

// ---------------------------------------------------------------------------
extern "C" void kernel_launch(void* const* d_in, const int* in_sizes, int n_in,
                              void* d_out, int out_size, void* d_ws, size_t ws_size,
                              hipStream_t stream) {
  const float* x      = (const float*)d_in[0];
  const int*   ei     = (const int*)d_in[1];
  const float* ec_w1  = (const float*)d_in[3];
  const float* ec_b1  = (const float*)d_in[4];
  const float* ec_w2  = (const float*)d_in[5];
  const float* ec_b2  = (const float*)d_in[6];
  const float* reg_w  = (const float*)d_in[7];
  const float* reg_b  = (const float*)d_in[8];
  const float* fin_w  = (const float*)d_in[9];
  const float* fin_b  = (const float*)d_in[10];
  const float* g1_w   = (const float*)d_in[11];
  const float* g1_as  = (const float*)d_in[12];
  const float* g1_ad  = (const float*)d_in[13];
  const float* g1_b   = (const float*)d_in[14];
  const float* g2_w   = (const float*)d_in[15];
  const float* g2_as  = (const float*)d_in[16];
  const float* g2_ad  = (const float*)d_in[17];
  const float* g2_b   = (const float*)d_in[18];
  const float* g3_w   = (const float*)d_in[19];
  const float* g3_as  = (const float*)d_in[20];
  const float* g3_ad  = (const float*)d_in[21];
  const float* g3_b   = (const float*)d_in[22];
  const float* g4_w   = (const float*)d_in[23];
  const float* g4_as  = (const float*)d_in[24];
  const float* g4_ad  = (const float*)d_in[25];
  const float* g4_b   = (const float*)d_in[26];

  const int N = in_sizes[0] / 128;
  const int E = in_sizes[1] / 2;

  char* base = (char*)d_ws;
  size_t off = 0;
  auto alloc = [&](size_t bytes) -> char* {
    char* p = base + off;
    off += (bytes + 255) & ~(size_t)255;
    return p;
  };
  const size_t szN4 = ((size_t)N * 4 + 255) & ~(size_t)255;
  int*   deg      = (int*)alloc((size_t)N * 4);
  int*   cnt      = (int*)alloc((size_t)N * 4);
  int*   rs       = (int*)alloc((size_t)(N + 1) * 4);
  int*   csr_src  = (int*)alloc((size_t)E * 4);
  int*   csr_dst  = (int*)alloc((size_t)E * 4);
  float* bias_cat = (float*)alloc(256 * 4);
  unsigned short* bcatTh = (unsigned short*)alloc(256 * 128 * 2);
  unsigned short* bcatTl = (unsigned short*)alloc(256 * 128 * 2);
  unsigned short* w2Th   = (unsigned short*)alloc(128 * 128 * 2);
  unsigned short* w2Tl   = (unsigned short*)alloc(128 * 128 * 2);
  unsigned short* g1Th   = (unsigned short*)alloc(256 * 128 * 2);
  unsigned short* g1Tl   = (unsigned short*)alloc(256 * 128 * 2);
  unsigned short* g2Th   = (unsigned short*)alloc(256 * 256 * 2);
  unsigned short* g2Tl   = (unsigned short*)alloc(256 * 256 * 2);
  unsigned short* g3Th   = (unsigned short*)alloc(256 * 256 * 2);
  unsigned short* g3Tl   = (unsigned short*)alloc(256 * 256 * 2);
  unsigned short* g4Th   = (unsigned short*)alloc(256 * 256 * 2);
  unsigned short* g4Tl   = (unsigned short*)alloc(256 * 256 * 2);
  unsigned short* regTh  = (unsigned short*)alloc(256 * 256 * 2);
  unsigned short* regTl  = (unsigned short*)alloc(256 * 256 * 2);
  float* uv = (float*)alloc((size_t)N * 256 * 4);
  float* x0 = (float*)alloc((size_t)N * 128 * 4);
  float* X1 = (float*)alloc((size_t)N * 256 * 4);
  float* X2 = (float*)alloc((size_t)N * 256 * 4);
  float* al = (float*)alloc((size_t)N * 4 * 4);
  unsigned short* s1h = (unsigned short*)alloc((size_t)N * 256 * 2);
  unsigned short* s1l = (unsigned short*)alloc((size_t)N * 256 * 2);
  unsigned short* s2h = (unsigned short*)alloc((size_t)N * 256 * 2);
  unsigned short* s2l = (unsigned short*)alloc((size_t)N * 256 * 2);
  (void)ws_size; (void)n_in; (void)out_size;

  const int nodeWaveBlocks = (N + 3) / 4;
  const dim3 gemmGrid((N + 63) / 64, 2);
  const int splitBlocks128 = (N * 128 / 4 + 255) / 256;

  // --- weight prep ---
  SplitJobs jobs;
  jobs.j[0] = {ec_w2, nullptr, w2Th, w2Tl, nullptr, 128, 128, 7, 0};
  jobs.j[1] = {g1_w,  nullptr, g1Th, g1Tl, nullptr, 128, 256, 7, 0};
  jobs.j[2] = {g2_w,  nullptr, g2Th, g2Tl, nullptr, 256, 256, 8, 0};
  jobs.j[3] = {g3_w,  nullptr, g3Th, g3Tl, nullptr, 256, 256, 8, 0};
  jobs.j[4] = {g4_w,  nullptr, g4Th, g4Tl, nullptr, 256, 256, 8, 0};
  jobs.j[5] = {reg_w, nullptr, regTh, regTl, nullptr, 256, 256, 8, 0};
  jobs.j[6] = {ec_w1, ec_b1, bcatTh, bcatTl, bias_cat, 128, 256, 7, 1};
  k_prep_all<<<dim3(256, 7), 256, 0, stream>>>(jobs);

  // --- CSR build ---
  hipMemsetAsync(deg, 0, 2 * szN4, stream);
  k_hist<<<(E + 255) / 256, 256, 0, stream>>>(ei, deg, E);
  k_scan<<<1, 1024, 0, stream>>>(deg, rs, N);
  k_scatter<<<(E + 255) / 256, 256, 0, stream>>>(ei, rs, cnt, csr_src, csr_dst, E);

  // --- EdgeConv ---
  k_split_act<<<splitBlocks128, 256, 0, stream>>>(x, s1h, s1l, N * 128, 0);
  k_gemm_mfma<<<gemmGrid, 256, 0, stream>>>(s1h, s1l, bcatTh, bcatTl, bias_cat, uv, N, 128,
                                            nullptr, nullptr, nullptr, nullptr, nullptr);
  k_fill_f32<<<(N * 128 + 255) / 256, 256, 0, stream>>>(x0, -INFINITY, N * 128);
  k_edgeconv2<<<(E + 63) / 64, 256, 0, stream>>>(uv, csr_src, csr_dst, w2Th, w2Tl, ec_b2, x0, E);
  k_split_act<<<splitBlocks128, 256, 0, stream>>>(x0, s1h, s1l, N * 128, 1);

  // --- GAT1: X1 = relu(gat(x0)) ---
  k_gemm_mfma<<<gemmGrid, 256, 0, stream>>>(s1h, s1l, g1Th, g1Tl, nullptr, uv, N, 128,
                                            nullptr, nullptr, g1_as, g1_ad, al);
  k_gat_agg<<<nodeWaveBlocks, 256, 0, stream>>>(uv, al, rs, csr_src, g1_b, nullptr, X1,
                                                s1h, s1l, nullptr, nullptr, N);

  // --- GAT2: X2 = relu(gat(X1)) + X1 ---
  k_gemm_mfma<<<gemmGrid, 256, 0, stream>>>(s1h, s1l, g2Th, g2Tl, nullptr, uv, N, 256,
                                            nullptr, nullptr, g2_as, g2_ad, al);
  k_gat_agg<<<nodeWaveBlocks, 256, 0, stream>>>(uv, al, rs, csr_src, g2_b, X1, X2,
                                                s2h, s2l, nullptr, nullptr, N);

  // --- reg: X1 = X2 @ reg_w + reg_b (fp32 + split) ---
  k_gemm_mfma<<<gemmGrid, 256, 0, stream>>>(s2h, s2l, regTh, regTl, reg_b, X1, N, 256,
                                            s1h, s1l, nullptr, nullptr, nullptr);

  // --- GAT3: X2 = relu(gat(X1)) + X1 ---
  k_gemm_mfma<<<gemmGrid, 256, 0, stream>>>(s1h, s1l, g3Th, g3Tl, nullptr, uv, N, 256,
                                            nullptr, nullptr, g3_as, g3_ad, al);
  k_gat_agg<<<nodeWaveBlocks, 256, 0, stream>>>(uv, al, rs, csr_src, g3_b, X1, X2,
                                                s2h, s2l, nullptr, nullptr, N);

  // --- GAT4 + final linear fused: out = relu(gat(X2)) @ fin_w + fin_b ---
  k_gemm_mfma<<<gemmGrid, 256, 0, stream>>>(s2h, s2l, g4Th, g4Tl, nullptr, uv, N, 256,
                                            nullptr, nullptr, g4_as, g4_ad, al);
  k_gat_agg<<<nodeWaveBlocks, 256, 0, stream>>>(uv, al, rs, csr_src, g4_b, nullptr,
                                                (float*)d_out, nullptr, nullptr,
                                                fin_w, fin_b, N);
}

// Round 8
// 533.758 us; speedup vs baseline: 1.3036x; 1.1594x over previous
//
#include <hip/hip_runtime.h>
#include <math.h>

// ---------------------------------------------------------------------------
// SymmetricalResidualGAT: EdgeConv(max) + GAT x4 (H=2, C=128) + linears.
// N=20000, E=320000. Round 8: GAT feature gather in bf16 (GEMM emits bf16-hi
// copy; agg gathers 8B/lane instead of 16B) — halves the dominant LLC traffic.
// Edgeconv run-merge tail parallelized across 2 row-halves.
// ---------------------------------------------------------------------------

#define NEG_SLOPE 0.2f

typedef short short8 __attribute__((ext_vector_type(8)));
typedef float float4v __attribute__((ext_vector_type(4)));
typedef unsigned short ushort4v __attribute__((ext_vector_type(4)));

#define AS1 __attribute__((address_space(1)))
#define AS3 __attribute__((address_space(3)))

__device__ __forceinline__ void cp16(const void* g, void* l) {
  __builtin_amdgcn_global_load_lds((const AS1 unsigned int*)g, (AS3 unsigned int*)l, 16, 0, 0);
}

__device__ __forceinline__ float leaky(float x) { return x > 0.f ? x : NEG_SLOPE * x; }

__device__ __forceinline__ void atomicMaxF(float* addr, float v) {
  if (v >= 0.f) atomicMax((int*)addr, __float_as_int(v));
  else          atomicMin((unsigned int*)addr, __float_as_uint(v));
}

__device__ __forceinline__ unsigned short bf16_rn(float f) {
  unsigned u = __float_as_uint(f);
  unsigned r = (u + 0x7FFFu + ((u >> 16) & 1u)) >> 16;
  return (unsigned short)r;
}
__device__ __forceinline__ float bf16_to_f(unsigned short h) {
  return __uint_as_float(((unsigned)h) << 16);
}
// load 4 bf16 (8B) -> float4
__device__ __forceinline__ float4 ld_bf4(const unsigned short* p) {
  ushort4v u = *(const ushort4v*)p;
  float4 f;
  f.x = bf16_to_f(u[0]); f.y = bf16_to_f(u[1]);
  f.z = bf16_to_f(u[2]); f.w = bf16_to_f(u[3]);
  return f;
}

// ---------------- small kernels ----------------
__global__ __launch_bounds__(256) void k_fill_f32(float* p, float v, int n) {
  int i = blockIdx.x * 256 + threadIdx.x;
  if (i < n) p[i] = v;
}

__global__ __launch_bounds__(256) void k_split_act(const float* __restrict__ src,
                                                   unsigned short* __restrict__ h,
                                                   unsigned short* __restrict__ l,
                                                   int n, int fixinf) {
  int i4 = (blockIdx.x * 256 + threadIdx.x) * 4;
  if (i4 >= n) return;
  float4 v = *(const float4*)&src[i4];
  if (fixinf) {
    if (v.x == -INFINITY) v.x = 0.f;
    if (v.y == -INFINITY) v.y = 0.f;
    if (v.z == -INFINITY) v.z = 0.f;
    if (v.w == -INFINITY) v.w = 0.f;
  }
  unsigned short hx = bf16_rn(v.x), hy = bf16_rn(v.y), hz = bf16_rn(v.z), hw = bf16_rn(v.w);
  ushort4v h4 = {hx, hy, hz, hw};
  ushort4v l4 = {bf16_rn(v.x - bf16_to_f(hx)), bf16_rn(v.y - bf16_to_f(hy)),
                 bf16_rn(v.z - bf16_to_f(hz)), bf16_rn(v.w - bf16_to_f(hw))};
  *(ushort4v*)&h[i4] = h4;
  *(ushort4v*)&l[i4] = l4;
}

__global__ __launch_bounds__(256) void k_hist(const int* __restrict__ ei, int* __restrict__ deg,
                                              int E) {
  int e = blockIdx.x * 256 + threadIdx.x;
  if (e < E) atomicAdd(&deg[ei[E + e]], 1);
}

__global__ __launch_bounds__(1024) void k_scan(const int* __restrict__ deg, int* __restrict__ rs,
                                               int n) {
  __shared__ int wsum[16];
  __shared__ int carry;
  int tid = threadIdx.x, lane = tid & 63, wv = tid >> 6;
  if (tid == 0) carry = 0;
  __syncthreads();
  for (int base = 0; base < n; base += 1024) {
    int i = base + tid;
    int v = (i < n) ? deg[i] : 0;
    int s = v;
    #pragma unroll
    for (int o = 1; o < 64; o <<= 1) {
      int t = __shfl(s, lane - o);
      if (lane >= o) s += t;
    }
    if (lane == 63) wsum[wv] = s;
    __syncthreads();
    if (wv == 0) {
      int x = (lane < 16) ? wsum[lane] : 0;
      #pragma unroll
      for (int o = 1; o < 16; o <<= 1) {
        int t = __shfl(x, lane - o);
        if (lane >= o) x += t;
      }
      if (lane < 16) wsum[lane] = x;
    }
    __syncthreads();
    int woff = carry + (wv ? wsum[wv - 1] : 0);
    if (i < n) rs[i] = woff + s - v;
    __syncthreads();
    if (tid == 0) carry += wsum[15];
    __syncthreads();
  }
  if (tid == 0) rs[n] = carry;
}

__global__ __launch_bounds__(256) void k_scatter(const int* __restrict__ ei,
                                                 const int* __restrict__ rs,
                                                 int* __restrict__ cnt,
                                                 int* __restrict__ csr_src,
                                                 int* __restrict__ csr_dst, int E) {
  int e = blockIdx.x * 256 + threadIdx.x;
  if (e < E) {
    int d = ei[E + e];
    int p = atomicAdd(&cnt[d], 1);
    int slot = rs[d] + p;
    csr_src[slot] = ei[e];
    csr_dst[slot] = d;
  }
}

// ---------------- one-shot weight prep: transpose + hi/lo bf16 split ----------------
struct SplitJob {
  const float* W;
  const float* aux;
  unsigned short* Th;
  unsigned short* Tl;
  float* bias_out;
  int K, N, kshift, type;
};
struct SplitJobs { SplitJob j[7]; };

__global__ __launch_bounds__(256) void k_prep_all(SplitJobs jobs) {
  SplitJob jb = jobs.j[blockIdx.y];
  int idx = blockIdx.x * 256 + threadIdx.x;
  if (idx >= jb.K * jb.N) return;
  float v;
  if (jb.type == 0) {
    int n = idx >> jb.kshift;
    int k = idx & (jb.K - 1);
    v = jb.W[k * jb.N + n];
  } else {
    int n = idx >> 7;
    int k = idx & 127;
    if (n < 128) v = jb.W[k * 128 + n] - jb.W[(k + 128) * 128 + n];
    else         v = jb.W[(k + 128) * 128 + (n - 128)];
    if (idx < 256) jb.bias_out[idx] = (idx < 128) ? jb.aux[idx] : 0.f;
  }
  unsigned short h = bf16_rn(v);
  jb.Th[idx] = h;
  jb.Tl[idx] = bf16_rn(v - bf16_to_f(h));
}

// ---------------- MFMA split-bf16 GEMM, 64x128 tile, LDS fragment-order ----------------
// Outputs (any subset): C fp32 (+bias), Ch/Cl split bf16, Cbf bf16-hi only.
__global__ __launch_bounds__(256) void k_gemm_mfma(const unsigned short* __restrict__ Ah,
                                                   const unsigned short* __restrict__ Al,
                                                   const unsigned short* __restrict__ BTh,
                                                   const unsigned short* __restrict__ BTl,
                                                   const float* __restrict__ bias,
                                                   float* __restrict__ C, int M, int K,
                                                   unsigned short* __restrict__ Ch,
                                                   unsigned short* __restrict__ Cl,
                                                   unsigned short* __restrict__ Cbf,
                                                   const float* __restrict__ a_s,
                                                   const float* __restrict__ a_d,
                                                   float* __restrict__ al_out) {
  __shared__ __align__(16) char sm[24576];   // AhS(4K) AlS(4K) BhS(8K) BlS(8K)
  __shared__ float alS[64][2];
  char* AhS = sm;
  char* AlS = sm + 4096;
  char* BhS = sm + 8192;
  char* BlS = sm + 16384;

  const int tid = threadIdx.x;
  const int bm = blockIdx.x * 64;
  const int bn = blockIdx.y * 128;
  const int w = tid >> 6, lane = tid & 63, quad = lane >> 4, lr = lane & 15;
  const int kq8 = quad * 8;

  float4v zero4 = {0.f, 0.f, 0.f, 0.f};
  float4v acc[4][2];
  #pragma unroll
  for (int mt = 0; mt < 4; ++mt)
    #pragma unroll
    for (int nt = 0; nt < 2; ++nt) acc[mt][nt] = zero4;

  int ar = bm + w * 16 + lr; if (ar >= M) ar = M - 1;
  const size_t aoff  = (size_t)ar * K + kq8;
  const size_t boff0 = (size_t)(bn + (2 * w) * 16 + lr) * K + kq8;
  const size_t boff1 = (size_t)(bn + (2 * w + 1) * 16 + lr) * K + kq8;
  char* lA   = AhS + w * 1024;
  char* lAl  = AlS + w * 1024;
  char* lB0  = BhS + (2 * w) * 1024;
  char* lB1  = BhS + (2 * w + 1) * 1024;
  char* lBl0 = BlS + (2 * w) * 1024;
  char* lBl1 = BlS + (2 * w + 1) * 1024;

  for (int k0 = 0; k0 < K; k0 += 32) {
    __syncthreads();
    cp16(Ah + aoff + k0, lA);
    cp16(Al + aoff + k0, lAl);
    cp16(BTh + boff0 + k0, lB0);
    cp16(BTh + boff1 + k0, lB1);
    cp16(BTl + boff0 + k0, lBl0);
    cp16(BTl + boff1 + k0, lBl1);
    __syncthreads();
    short8 ah[4], alo[4], bh[2], blo[2];
    #pragma unroll
    for (int mt = 0; mt < 4; ++mt) {
      ah[mt]  = *(const short8*)(AhS + mt * 1024 + lane * 16);
      alo[mt] = *(const short8*)(AlS + mt * 1024 + lane * 16);
    }
    #pragma unroll
    for (int nt = 0; nt < 2; ++nt) {
      bh[nt]  = *(const short8*)(BhS + (2 * w + nt) * 1024 + lane * 16);
      blo[nt] = *(const short8*)(BlS + (2 * w + nt) * 1024 + lane * 16);
    }
    #pragma unroll
    for (int mt = 0; mt < 4; ++mt)
      #pragma unroll
      for (int nt = 0; nt < 2; ++nt) {
        acc[mt][nt] = __builtin_amdgcn_mfma_f32_16x16x32_bf16(ah[mt], bh[nt], acc[mt][nt], 0, 0, 0);
        acc[mt][nt] = __builtin_amdgcn_mfma_f32_16x16x32_bf16(alo[mt], bh[nt], acc[mt][nt], 0, 0, 0);
        acc[mt][nt] = __builtin_amdgcn_mfma_f32_16x16x32_bf16(ah[mt], blo[nt], acc[mt][nt], 0, 0, 0);
      }
  }
  // ---- epilogue stores (C layout col=lane&15, row=quad*4+reg) ----
  #pragma unroll
  for (int nt = 0; nt < 2; ++nt) {
    int n = bn + w * 32 + nt * 16 + lr;
    float bv = bias ? bias[n] : 0.f;
    #pragma unroll
    for (int mt = 0; mt < 4; ++mt) {
      #pragma unroll
      for (int r = 0; r < 4; ++r) {
        int m = bm + mt * 16 + quad * 4 + r;
        if (m < M) {
          float v = acc[mt][nt][r] + bv;
          size_t idx = (size_t)m * 256 + n;
          if (C) C[idx] = v;
          if (Cbf) Cbf[idx] = bf16_rn(v);
          if (Ch) {
            unsigned short h = bf16_rn(v);
            Ch[idx] = h;
            Cl[idx] = bf16_rn(v - bf16_to_f(h));
          }
        }
      }
    }
  }
  // ---- fused attention logits (block y == head) ----
  if (a_s) {
    if (tid < 128) ((float*)alS)[tid] = 0.f;
    __syncthreads();
    float asv[2], adv[2];
    #pragma unroll
    for (int nt = 0; nt < 2; ++nt) {
      int n = bn + w * 32 + nt * 16 + lr;
      asv[nt] = a_s[n];
      adv[nt] = a_d[n];
    }
    #pragma unroll
    for (int mt = 0; mt < 4; ++mt) {
      #pragma unroll
      for (int r = 0; r < 4; ++r) {
        float ps = acc[mt][0][r] * asv[0] + acc[mt][1][r] * asv[1];
        float pd = acc[mt][0][r] * adv[0] + acc[mt][1][r] * adv[1];
        #pragma unroll
        for (int o = 8; o; o >>= 1) {
          ps += __shfl_xor(ps, o);
          pd += __shfl_xor(pd, o);
        }
        if (lr == 0) {
          int row = mt * 16 + quad * 4 + r;
          atomicAdd(&alS[row][0], ps);
          atomicAdd(&alS[row][1], pd);
        }
      }
    }
    __syncthreads();
    int head = bn >> 7;
    if (tid < 64) {
      int m = bm + tid;
      if (m < M) {
        al_out[m * 4 + head]     = alS[tid][0];
        al_out[m * 4 + 2 + head] = alS[tid][1];
      }
    }
  }
}

// ---------------- EdgeConv: P=relu(u[dst]+v[src]); H2=P@W2+b2; segment-max ----------------
__global__ __launch_bounds__(256, 4) void k_edgeconv2(const float* __restrict__ uv,
                                                      const int* __restrict__ csr_src,
                                                      const int* __restrict__ csr_dst,
                                                      const unsigned short* __restrict__ w2Th,
                                                      const unsigned short* __restrict__ w2Tl,
                                                      const float* __restrict__ b2,
                                                      float* __restrict__ x0, int E) {
  __shared__ __align__(16) char smem[34816];
  unsigned short (*Ph)[136] = (unsigned short(*)[136])smem;            // 17408 B
  unsigned short (*Pl)[136] = (unsigned short(*)[136])(smem + 17408);  // 17408 B
  float (*H2)[132] = (float(*)[132])smem;                              // alias, 33792 B
  __shared__ int sSrc[64], sDst[64];

  const int tid = threadIdx.x;
  const int e0 = blockIdx.x * 64;
  const int w = tid >> 6, lane = tid & 63, quad = lane >> 4, lr = lane & 15;
  if (tid < 64) {
    int e = e0 + tid;
    sSrc[tid] = (e < E) ? csr_src[e] : -1;
    sDst[tid] = (e < E) ? csr_dst[e] : -1;
  }
  __syncthreads();
  #pragma unroll
  for (int c = tid; c < 1024; c += 256) {
    int r = c >> 4;
    int kq = (c & 15) * 8;
    float pv[8];
    int sn = sSrc[r], dn = sDst[r];
    if (sn >= 0) {
      float4 u0 = *(const float4*)&uv[(size_t)dn * 256 + kq];
      float4 u1 = *(const float4*)&uv[(size_t)dn * 256 + kq + 4];
      float4 v0 = *(const float4*)&uv[(size_t)sn * 256 + 128 + kq];
      float4 v1 = *(const float4*)&uv[(size_t)sn * 256 + 128 + kq + 4];
      pv[0] = fmaxf(u0.x + v0.x, 0.f); pv[1] = fmaxf(u0.y + v0.y, 0.f);
      pv[2] = fmaxf(u0.z + v0.z, 0.f); pv[3] = fmaxf(u0.w + v0.w, 0.f);
      pv[4] = fmaxf(u1.x + v1.x, 0.f); pv[5] = fmaxf(u1.y + v1.y, 0.f);
      pv[6] = fmaxf(u1.z + v1.z, 0.f); pv[7] = fmaxf(u1.w + v1.w, 0.f);
    } else {
      #pragma unroll
      for (int i = 0; i < 8; ++i) pv[i] = 0.f;
    }
    short8 h8, l8;
    #pragma unroll
    for (int i = 0; i < 8; ++i) {
      unsigned short h = bf16_rn(pv[i]);
      h8[i] = (short)h;
      l8[i] = (short)bf16_rn(pv[i] - bf16_to_f(h));
    }
    *(short8*)&Ph[r][kq] = h8;
    *(short8*)&Pl[r][kq] = l8;
  }
  __syncthreads();
  float4v zero4 = {0.f, 0.f, 0.f, 0.f};
  float4v acc[4][2];
  #pragma unroll
  for (int mt = 0; mt < 4; ++mt)
    #pragma unroll
    for (int nt = 0; nt < 2; ++nt) acc[mt][nt] = zero4;

  #pragma unroll
  for (int k0 = 0; k0 < 128; k0 += 32) {
    short8 ah[4], alo[4], bh[2], blo[2];
    #pragma unroll
    for (int nt = 0; nt < 2; ++nt) {
      int n = w * 32 + nt * 16 + lr;
      bh[nt]  = *(const short8*)&w2Th[(size_t)n * 128 + k0 + quad * 8];
      blo[nt] = *(const short8*)&w2Tl[(size_t)n * 128 + k0 + quad * 8];
    }
    #pragma unroll
    for (int mt = 0; mt < 4; ++mt) {
      ah[mt]  = *(short8*)&Ph[mt * 16 + lr][k0 + quad * 8];
      alo[mt] = *(short8*)&Pl[mt * 16 + lr][k0 + quad * 8];
    }
    #pragma unroll
    for (int mt = 0; mt < 4; ++mt)
      #pragma unroll
      for (int nt = 0; nt < 2; ++nt) {
        acc[mt][nt] = __builtin_amdgcn_mfma_f32_16x16x32_bf16(ah[mt], bh[nt], acc[mt][nt], 0, 0, 0);
        acc[mt][nt] = __builtin_amdgcn_mfma_f32_16x16x32_bf16(alo[mt], bh[nt], acc[mt][nt], 0, 0, 0);
        acc[mt][nt] = __builtin_amdgcn_mfma_f32_16x16x32_bf16(ah[mt], blo[nt], acc[mt][nt], 0, 0, 0);
      }
  }
  __syncthreads();  // P dead; reuse as H2
  #pragma unroll
  for (int nt = 0; nt < 2; ++nt) {
    int n = w * 32 + nt * 16 + lr;
    float bv = b2[n];
    #pragma unroll
    for (int mt = 0; mt < 4; ++mt) {
      #pragma unroll
      for (int r = 0; r < 4; ++r) {
        int row = mt * 16 + quad * 4 + r;
        H2[row][n] = acc[mt][nt][r] + bv;
      }
    }
  }
  __syncthreads();
  // run-merge: 256 threads = 2 row-halves x 128 cols; boundary run is safe
  // because both halves finish with atomicMaxF on the same dst.
  {
    int half = tid >> 7;        // 0 or 1
    int col = tid & 127;
    int r0 = half * 32;
    int prev = sDst[r0];
    float rmax = H2[r0][col];
    for (int r = r0 + 1; r < r0 + 32; ++r) {
      int d = sDst[r];
      float v = H2[r][col];
      if (d == prev) {
        rmax = fmaxf(rmax, v);
      } else {
        if (prev >= 0) atomicMaxF(&x0[(size_t)prev * 128 + col], rmax);
        prev = d;
        rmax = v;
      }
    }
    if (prev >= 0) atomicMaxF(&x0[(size_t)prev * 128 + col], rmax);
  }
}

// ---------------- GAT segment softmax + aggregation, one wave per node ----------------
// Features gathered from bf16 copy Hfb. If finw != null: out[i]=dot(feat,finw)+finb.
__global__ __launch_bounds__(256) void k_gat_agg(const unsigned short* __restrict__ Hfb,
                                                 const float* __restrict__ al,
                                                 const int* __restrict__ rs,
                                                 const int* __restrict__ csr_src,
                                                 const float* __restrict__ bias,
                                                 const float* __restrict__ res,
                                                 float* __restrict__ out,
                                                 unsigned short* __restrict__ outh,
                                                 unsigned short* __restrict__ outl,
                                                 const float* __restrict__ finw,
                                                 const float* __restrict__ finb, int N) {
  int wave = threadIdx.x >> 6, lane = threadIdx.x & 63;
  int i = blockIdx.x * 4 + wave;
  if (i >= N) return;
  int beg = rs[i], end = rs[i + 1];
  int deg = end - beg;
  float4 me = *(const float4*)&al[i * 4];
  float ad0 = me.z, ad1 = me.w;
  float sl0 = leaky(me.x + ad0);
  float sl1 = leaky(me.y + ad1);
  const int c = lane << 2;
  const int hsel = lane >> 5;
  float a0, a1, a2, a3;

  if (deg <= 64) {
    int s = 0;
    float l0 = -INFINITY, l1 = -INFINITY;
    bool act = lane < deg;
    if (act) {
      s = csr_src[beg + lane];
      float4 a4 = *(const float4*)&al[s * 4];
      l0 = leaky(a4.x + ad0);
      l1 = leaky(a4.y + ad1);
    }
    float m0 = fmaxf(sl0, l0), m1 = fmaxf(sl1, l1);
    #pragma unroll
    for (int o = 32; o; o >>= 1) {
      m0 = fmaxf(m0, __shfl_xor(m0, o));
      m1 = fmaxf(m1, __shfl_xor(m1, o));
    }
    float w0 = act ? __expf(l0 - m0) : 0.f;
    float w1 = act ? __expf(l1 - m1) : 0.f;
    float s0 = w0, s1 = w1;
    #pragma unroll
    for (int o = 32; o; o >>= 1) {
      s0 += __shfl_xor(s0, o);
      s1 += __shfl_xor(s1, o);
    }
    s0 += __expf(sl0 - m0);
    s1 += __expf(sl1 - m1);
    float inv0 = 1.f / (s0 + 1e-16f), inv1 = 1.f / (s1 + 1e-16f);
    float wp0 = w0 * inv0, wp1 = w1 * inv1;
    float wself = hsel ? __expf(sl1 - m1) * inv1 : __expf(sl0 - m0) * inv0;
    float4 hv = ld_bf4(&Hfb[(size_t)i * 256 + c]);
    a0 = wself * hv.x; a1 = wself * hv.y; a2 = wself * hv.z; a3 = wself * hv.w;
    float b0 = 0.f, b1 = 0.f, b2 = 0.f, b3 = 0.f;
    float c0 = 0.f, c1 = 0.f, c2 = 0.f, c3 = 0.f;
    float d0 = 0.f, d1 = 0.f, d2 = 0.f, d3 = 0.f;
    int j = 0;
    for (; j + 8 <= deg; j += 8) {
      int   sjj[8];
      float wjj[8];
      #pragma unroll
      for (int q = 0; q < 8; ++q) {
        sjj[q] = __shfl(s, j + q);
        // shuffle BOTH head weights; select with RECEIVER's hsel (R6 bug)
        float wA = __shfl(wp0, j + q);
        float wB = __shfl(wp1, j + q);
        wjj[q] = hsel ? wB : wA;
      }
      float4 h0 = ld_bf4(&Hfb[(size_t)sjj[0] * 256 + c]);
      float4 h1 = ld_bf4(&Hfb[(size_t)sjj[1] * 256 + c]);
      float4 h2 = ld_bf4(&Hfb[(size_t)sjj[2] * 256 + c]);
      float4 h3 = ld_bf4(&Hfb[(size_t)sjj[3] * 256 + c]);
      float4 h4 = ld_bf4(&Hfb[(size_t)sjj[4] * 256 + c]);
      float4 h5 = ld_bf4(&Hfb[(size_t)sjj[5] * 256 + c]);
      float4 h6 = ld_bf4(&Hfb[(size_t)sjj[6] * 256 + c]);
      float4 h7 = ld_bf4(&Hfb[(size_t)sjj[7] * 256 + c]);
      a0 += wjj[0] * h0.x; a1 += wjj[0] * h0.y; a2 += wjj[0] * h0.z; a3 += wjj[0] * h0.w;
      b0 += wjj[1] * h1.x; b1 += wjj[1] * h1.y; b2 += wjj[1] * h1.z; b3 += wjj[1] * h1.w;
      c0 += wjj[2] * h2.x; c1 += wjj[2] * h2.y; c2 += wjj[2] * h2.z; c3 += wjj[2] * h2.w;
      d0 += wjj[3] * h3.x; d1 += wjj[3] * h3.y; d2 += wjj[3] * h3.z; d3 += wjj[3] * h3.w;
      a0 += wjj[4] * h4.x; a1 += wjj[4] * h4.y; a2 += wjj[4] * h4.z; a3 += wjj[4] * h4.w;
      b0 += wjj[5] * h5.x; b1 += wjj[5] * h5.y; b2 += wjj[5] * h5.z; b3 += wjj[5] * h5.w;
      c0 += wjj[6] * h6.x; c1 += wjj[6] * h6.y; c2 += wjj[6] * h6.z; c3 += wjj[6] * h6.w;
      d0 += wjj[7] * h7.x; d1 += wjj[7] * h7.y; d2 += wjj[7] * h7.z; d3 += wjj[7] * h7.w;
    }
    for (; j < deg; ++j) {
      int sj = __shfl(s, j);
      float wA = __shfl(wp0, j);
      float wB = __shfl(wp1, j);
      float wj = hsel ? wB : wA;
      float4 h4 = ld_bf4(&Hfb[(size_t)sj * 256 + c]);
      a0 += wj * h4.x; a1 += wj * h4.y; a2 += wj * h4.z; a3 += wj * h4.w;
    }
    a0 += b0 + c0 + d0; a1 += b1 + c1 + d1;
    a2 += b2 + c2 + d2; a3 += b3 + c3 + d3;
  } else {
    float m0 = sl0, m1 = sl1;
    for (int e = beg + lane; e < end; e += 64) {
      int s = csr_src[e];
      m0 = fmaxf(m0, leaky(al[s * 4 + 0] + ad0));
      m1 = fmaxf(m1, leaky(al[s * 4 + 1] + ad1));
    }
    #pragma unroll
    for (int o = 32; o; o >>= 1) {
      m0 = fmaxf(m0, __shfl_xor(m0, o));
      m1 = fmaxf(m1, __shfl_xor(m1, o));
    }
    float s0 = 0.f, s1 = 0.f;
    for (int e = beg + lane; e < end; e += 64) {
      int s = csr_src[e];
      s0 += __expf(leaky(al[s * 4 + 0] + ad0) - m0);
      s1 += __expf(leaky(al[s * 4 + 1] + ad1) - m1);
    }
    #pragma unroll
    for (int o = 32; o; o >>= 1) {
      s0 += __shfl_xor(s0, o);
      s1 += __shfl_xor(s1, o);
    }
    s0 += __expf(sl0 - m0);
    s1 += __expf(sl1 - m1);
    float inv0 = 1.f / (s0 + 1e-16f), inv1 = 1.f / (s1 + 1e-16f);
    float mh = hsel ? m1 : m0;
    float invh = hsel ? inv1 : inv0;
    float adh = hsel ? ad1 : ad0;
    float wself = __expf((hsel ? sl1 : sl0) - mh) * invh;
    float4 hv = ld_bf4(&Hfb[(size_t)i * 256 + c]);
    a0 = wself * hv.x; a1 = wself * hv.y; a2 = wself * hv.z; a3 = wself * hv.w;
    for (int e = beg; e < end; ++e) {
      int s = csr_src[e];
      float wgt = __expf(leaky(al[s * 4 + hsel] + adh) - mh) * invh;
      float4 h4 = ld_bf4(&Hfb[(size_t)s * 256 + c]);
      a0 += wgt * h4.x; a1 += wgt * h4.y; a2 += wgt * h4.z; a3 += wgt * h4.w;
    }
  }
  float4 bv = *(const float4*)&bias[c];
  float4 o4;
  o4.x = fmaxf(a0 + bv.x, 0.f);
  o4.y = fmaxf(a1 + bv.y, 0.f);
  o4.z = fmaxf(a2 + bv.z, 0.f);
  o4.w = fmaxf(a3 + bv.w, 0.f);
  if (res) {
    float4 r4 = *(const float4*)&res[(size_t)i * 256 + c];
    o4.x += r4.x; o4.y += r4.y; o4.z += r4.z; o4.w += r4.w;
  }
  if (finw) {
    float4 wv = *(const float4*)&finw[c];
    float p = o4.x * wv.x + o4.y * wv.y + o4.z * wv.z + o4.w * wv.w;
    #pragma unroll
    for (int o = 32; o; o >>= 1) p += __shfl_xor(p, o);
    if (lane == 0) out[i] = p + finb[0];
    return;
  }
  size_t idx = (size_t)i * 256 + c;
  *(float4*)&out[idx] = o4;
  if (outh) {
    unsigned short hx = bf16_rn(o4.x), hy = bf16_rn(o4.y), hz = bf16_rn(o4.z), hw = bf16_rn(o4.w);
    ushort4v h4 = {hx, hy, hz, hw};
    ushort4v l4 = {bf16_rn(o4.x - bf16_to_f(hx)), bf16_rn(o4.y - bf16_to_f(hy)),
                   bf16_rn(o4.z - bf16_to_f(hz)), bf16_rn(o4.w - bf16_to_f(hw))};
    *(ushort4v*)&outh[idx] = h4;
    *(ushort4v*)&outl[idx] = l4;
  }
}

// ---------------------------------------------------------------------------
extern "C" void kernel_launch(void* const* d_in, const int* in_sizes, int n_in,
                              void* d_out, int out_size, void* d_ws, size_t ws_size,
                              hipStream_t stream) {
  const float* x      = (const float*)d_in[0];
  const int*   ei     = (const int*)d_in[1];
  const float* ec_w1  = (const float*)d_in[3];
  const float* ec_b1  = (const float*)d_in[4];
  const float* ec_w2  = (const float*)d_in[5];
  const float* ec_b2  = (const float*)d_in[6];
  const float* reg_w  = (const float*)d_in[7];
  const float* reg_b  = (const float*)d_in[8];
  const float* fin_w  = (const float*)d_in[9];
  const float* fin_b  = (const float*)d_in[10];
  const float* g1_w   = (const float*)d_in[11];
  const float* g1_as  = (const float*)d_in[12];
  const float* g1_ad  = (const float*)d_in[13];
  const float* g1_b   = (const float*)d_in[14];
  const float* g2_w   = (const float*)d_in[15];
  const float* g2_as  = (const float*)d_in[16];
  const float* g2_ad  = (const float*)d_in[17];
  const float* g2_b   = (const float*)d_in[18];
  const float* g3_w   = (const float*)d_in[19];
  const float* g3_as  = (const float*)d_in[20];
  const float* g3_ad  = (const float*)d_in[21];
  const float* g3_b   = (const float*)d_in[22];
  const float* g4_w   = (const float*)d_in[23];
  const float* g4_as  = (const float*)d_in[24];
  const float* g4_ad  = (const float*)d_in[25];
  const float* g4_b   = (const float*)d_in[26];

  const int N = in_sizes[0] / 128;
  const int E = in_sizes[1] / 2;

  char* base = (char*)d_ws;
  size_t off = 0;
  auto alloc = [&](size_t bytes) -> char* {
    char* p = base + off;
    off += (bytes + 255) & ~(size_t)255;
    return p;
  };
  const size_t szN4 = ((size_t)N * 4 + 255) & ~(size_t)255;
  int*   deg      = (int*)alloc((size_t)N * 4);
  int*   cnt      = (int*)alloc((size_t)N * 4);
  int*   rs       = (int*)alloc((size_t)(N + 1) * 4);
  int*   csr_src  = (int*)alloc((size_t)E * 4);
  int*   csr_dst  = (int*)alloc((size_t)E * 4);
  float* bias_cat = (float*)alloc(256 * 4);
  unsigned short* bcatTh = (unsigned short*)alloc(256 * 128 * 2);
  unsigned short* bcatTl = (unsigned short*)alloc(256 * 128 * 2);
  unsigned short* w2Th   = (unsigned short*)alloc(128 * 128 * 2);
  unsigned short* w2Tl   = (unsigned short*)alloc(128 * 128 * 2);
  unsigned short* g1Th   = (unsigned short*)alloc(256 * 128 * 2);
  unsigned short* g1Tl   = (unsigned short*)alloc(256 * 128 * 2);
  unsigned short* g2Th   = (unsigned short*)alloc(256 * 256 * 2);
  unsigned short* g2Tl   = (unsigned short*)alloc(256 * 256 * 2);
  unsigned short* g3Th   = (unsigned short*)alloc(256 * 256 * 2);
  unsigned short* g3Tl   = (unsigned short*)alloc(256 * 256 * 2);
  unsigned short* g4Th   = (unsigned short*)alloc(256 * 256 * 2);
  unsigned short* g4Tl   = (unsigned short*)alloc(256 * 256 * 2);
  unsigned short* regTh  = (unsigned short*)alloc(256 * 256 * 2);
  unsigned short* regTl  = (unsigned short*)alloc(256 * 256 * 2);
  float* uv  = (float*)alloc((size_t)N * 256 * 4);
  unsigned short* uvh = (unsigned short*)alloc((size_t)N * 256 * 2);
  float* x0 = (float*)alloc((size_t)N * 128 * 4);
  float* X1 = (float*)alloc((size_t)N * 256 * 4);
  float* X2 = (float*)alloc((size_t)N * 256 * 4);
  float* al = (float*)alloc((size_t)N * 4 * 4);
  unsigned short* s1h = (unsigned short*)alloc((size_t)N * 256 * 2);
  unsigned short* s1l = (unsigned short*)alloc((size_t)N * 256 * 2);
  unsigned short* s2h = (unsigned short*)alloc((size_t)N * 256 * 2);
  unsigned short* s2l = (unsigned short*)alloc((size_t)N * 256 * 2);
  (void)ws_size; (void)n_in; (void)out_size;

  const int nodeWaveBlocks = (N + 3) / 4;
  const dim3 gemmGrid((N + 63) / 64, 2);
  const int splitBlocks128 = (N * 128 / 4 + 255) / 256;

  // --- weight prep ---
  SplitJobs jobs;
  jobs.j[0] = {ec_w2, nullptr, w2Th, w2Tl, nullptr, 128, 128, 7, 0};
  jobs.j[1] = {g1_w,  nullptr, g1Th, g1Tl, nullptr, 128, 256, 7, 0};
  jobs.j[2] = {g2_w,  nullptr, g2Th, g2Tl, nullptr, 256, 256, 8, 0};
  jobs.j[3] = {g3_w,  nullptr, g3Th, g3Tl, nullptr, 256, 256, 8, 0};
  jobs.j[4] = {g4_w,  nullptr, g4Th, g4Tl, nullptr, 256, 256, 8, 0};
  jobs.j[5] = {reg_w, nullptr, regTh, regTl, nullptr, 256, 256, 8, 0};
  jobs.j[6] = {ec_w1, ec_b1, bcatTh, bcatTl, bias_cat, 128, 256, 7, 1};
  k_prep_all<<<dim3(256, 7), 256, 0, stream>>>(jobs);

  // --- CSR build ---
  hipMemsetAsync(deg, 0, 2 * szN4, stream);
  k_hist<<<(E + 255) / 256, 256, 0, stream>>>(ei, deg, E);
  k_scan<<<1, 1024, 0, stream>>>(deg, rs, N);
  k_scatter<<<(E + 255) / 256, 256, 0, stream>>>(ei, rs, cnt, csr_src, csr_dst, E);

  // --- EdgeConv ---
  k_split_act<<<splitBlocks128, 256, 0, stream>>>(x, s1h, s1l, N * 128, 0);
  k_gemm_mfma<<<gemmGrid, 256, 0, stream>>>(s1h, s1l, bcatTh, bcatTl, bias_cat, uv, N, 128,
                                            nullptr, nullptr, nullptr,
                                            nullptr, nullptr, nullptr);
  k_fill_f32<<<(N * 128 + 255) / 256, 256, 0, stream>>>(x0, -INFINITY, N * 128);
  k_edgeconv2<<<(E + 63) / 64, 256, 0, stream>>>(uv, csr_src, csr_dst, w2Th, w2Tl, ec_b2, x0, E);
  k_split_act<<<splitBlocks128, 256, 0, stream>>>(x0, s1h, s1l, N * 128, 1);

  // --- GAT1: X1 = relu(gat(x0)) ---
  k_gemm_mfma<<<gemmGrid, 256, 0, stream>>>(s1h, s1l, g1Th, g1Tl, nullptr, nullptr, N, 128,
                                            nullptr, nullptr, uvh, g1_as, g1_ad, al);
  k_gat_agg<<<nodeWaveBlocks, 256, 0, stream>>>(uvh, al, rs, csr_src, g1_b, nullptr, X1,
                                                s1h, s1l, nullptr, nullptr, N);

  // --- GAT2: X2 = relu(gat(X1)) + X1 ---
  k_gemm_mfma<<<gemmGrid, 256, 0, stream>>>(s1h, s1l, g2Th, g2Tl, nullptr, nullptr, N, 256,
                                            nullptr, nullptr, uvh, g2_as, g2_ad, al);
  k_gat_agg<<<nodeWaveBlocks, 256, 0, stream>>>(uvh, al, rs, csr_src, g2_b, X1, X2,
                                                s2h, s2l, nullptr, nullptr, N);

  // --- reg: X1 = X2 @ reg_w + reg_b (fp32 + split) ---
  k_gemm_mfma<<<gemmGrid, 256, 0, stream>>>(s2h, s2l, regTh, regTl, reg_b, X1, N, 256,
                                            s1h, s1l, nullptr, nullptr, nullptr, nullptr);

  // --- GAT3: X2 = relu(gat(X1)) + X1 ---
  k_gemm_mfma<<<gemmGrid, 256, 0, stream>>>(s1h, s1l, g3Th, g3Tl, nullptr, nullptr, N, 256,
                                            nullptr, nullptr, uvh, g3_as, g3_ad, al);
  k_gat_agg<<<nodeWaveBlocks, 256, 0, stream>>>(uvh, al, rs, csr_src, g3_b, X1, X2,
                                                s2h, s2l, nullptr, nullptr, N);

  // --- GAT4 + final linear fused ---
  k_gemm_mfma<<<gemmGrid, 256, 0, stream>>>(s2h, s2l, g4Th, g4Tl, nullptr, nullptr, N, 256,
                                            nullptr, nullptr, uvh, g4_as, g4_ad, al);
  k_gat_agg<<<nodeWaveBlocks, 256, 0, stream>>>(uvh, al, rs, csr_src, g4_b, nullptr,
                                                (float*)d_out, nullptr, nullptr,
                                                fin_w, fin_b, N);
}